// Round 6
// baseline (1912.885 us; speedup 1.0000x reference)
//
#include <hip/hip_runtime.h>

// LightGCN 3-hop propagation, D=64, bf16 features / fp32 accumulate.
// R6: eliminate ALL global atomics from the CSR build. R5 counters showed
// hist_rank_k (1.6M atomic-with-return) at 68us with VALUBusy 0.5%, HBM 11%
// -> memory-side RMW write-through bound (56MB WRITE_SIZE, ~35B/atomic).
// New structure: 16-row buckets (6250), 3-pass privatized partition using
// only LDS atomics; spmm accumulates per-bucket tiles in wave-private LDS
// (ds_add_f32, 2 lanes/bank = conflict-free) so no stable rank is needed.

#define NBUCKET 6250     // N=100000 rows, 16 per bucket
#define BSHIFT  4
#define BMASK   15
#define NCHUNK  256      // edge chunks; E=1.6M -> 6250 edges/chunk

static __device__ __forceinline__ ushort f2bf(float f) {
    unsigned u = __float_as_uint(f);
    unsigned r = (u + 0x7fffu + ((u >> 16) & 1u)) >> 16;   // RNE
    return (ushort)r;
}
static __device__ __forceinline__ float bf2f(ushort b) {
    return __uint_as_float(((unsigned)b) << 16);
}

__global__ __launch_bounds__(256) void f2bf_k(
    const float* __restrict__ in, ushort* __restrict__ out, int n4)
{
    int i = blockIdx.x * blockDim.x + threadIdx.x;
    if (i >= n4) return;
    float4 v = *(const float4*)(in + (long)i * 4);
    ushort4 o;
    o.x = f2bf(v.x); o.y = f2bf(v.y); o.z = f2bf(v.z); o.w = f2bf(v.w);
    *(ushort4*)(out + (long)i * 4) = o;
}

// pass A: per-chunk bucket histogram in LDS (no global atomics)
__global__ __launch_bounds__(256) void count_k(
    const int* __restrict__ rows, int* __restrict__ cnt, int E, int chunkE)
{
    __shared__ unsigned h[NBUCKET];
    int c = blockIdx.x;
    for (int b = threadIdx.x; b < NBUCKET; b += 256) h[b] = 0u;
    __syncthreads();
    int s = c * chunkE;
    int e = min(s + chunkE, E);
    for (int j = s + (int)threadIdx.x; j < e; j += 256)
        atomicAdd(&h[rows[j] >> BSHIFT], 1u);
    __syncthreads();
    int* o = cnt + (long)c * NBUCKET;
    for (int b = threadIdx.x; b < NBUCKET; b += 256) o[b] = (int)h[b];
}

// pass B1: totals[b] = sum_c cnt[c][b]   (coalesced across bucket axis)
__global__ __launch_bounds__(256) void totals_k(
    const int* __restrict__ cnt, int* __restrict__ totals, int nchunk)
{
    int b = blockIdx.x * 256 + threadIdx.x;
    if (b >= NBUCKET) return;
    int t = 0;
    for (int c = 0; c < nchunk; ++c) t += cnt[(long)c * NBUCKET + b];
    totals[b] = t;
}

__global__ __launch_bounds__(256) void block_sums_k(
    const int* __restrict__ counts, int* __restrict__ bsums, int N)
{
    __shared__ int sm[256];
    int i = blockIdx.x * 256 + threadIdx.x;
    sm[threadIdx.x] = (i < N) ? counts[i] : 0;
    __syncthreads();
    for (int off = 128; off > 0; off >>= 1) {
        if (threadIdx.x < off) sm[threadIdx.x] += sm[threadIdx.x + off];
        __syncthreads();
    }
    if (threadIdx.x == 0) bsums[blockIdx.x] = sm[0];
}

__global__ __launch_bounds__(512) void scan_bsums_k(
    const int* __restrict__ bsums, int* __restrict__ bprefix, int nb)
{
    __shared__ int sm[512];
    int t = threadIdx.x;
    int v = (t < nb) ? bsums[t] : 0;
    sm[t] = v;
    __syncthreads();
    for (int off = 1; off < 512; off <<= 1) {
        int add = (t >= off) ? sm[t - off] : 0;
        __syncthreads();
        sm[t] += add;
        __syncthreads();
    }
    if (t < nb) bprefix[t] = sm[t] - v;   // exclusive prefix of block sums
}

__global__ __launch_bounds__(256) void scan_counts_k(
    const int* __restrict__ counts, const int* __restrict__ bprefix,
    int* __restrict__ bucket_start, int N)
{
    __shared__ int sm[256];
    int i = blockIdx.x * 256 + threadIdx.x;
    int c = (i < N) ? counts[i] : 0;
    sm[threadIdx.x] = c;
    __syncthreads();
    for (int off = 1; off < 256; off <<= 1) {
        int add = (threadIdx.x >= off) ? sm[threadIdx.x - off] : 0;
        __syncthreads();
        sm[threadIdx.x] += add;
        __syncthreads();
    }
    if (i < N) {
        int excl = sm[threadIdx.x] - c + bprefix[blockIdx.x];
        bucket_start[i] = excl;
        if (i == N - 1) bucket_start[N] = excl + c;   // == E
    }
}

// pass B2: cnt[c][b] <- global base offset for (chunk c, bucket b), in place
__global__ __launch_bounds__(256) void offs_k(
    int* __restrict__ cnt, const int* __restrict__ bucket_start, int nchunk)
{
    int b = blockIdx.x * 256 + threadIdx.x;
    if (b >= NBUCKET) return;
    int base = bucket_start[b];
    for (int c = 0; c < nchunk; ++c) {
        long i = (long)c * NBUCKET + b;
        int v = cnt[i];
        cnt[i] = base;
        base += v;
    }
}

// pass C: partition edges into bucket segments; LDS cursors only.
// edge payload: .x = (row&15)<<17 | col  (col < 2^17), .y = val bits
__global__ __launch_bounds__(256) void scatter3_k(
    const int* __restrict__ rows, const int* __restrict__ cols,
    const float* __restrict__ vals, const int* __restrict__ offs,
    int2* __restrict__ edges, int E, int chunkE)
{
    __shared__ int cur[NBUCKET];
    int c = blockIdx.x;
    const int* o = offs + (long)c * NBUCKET;
    for (int b = threadIdx.x; b < NBUCKET; b += 256) cur[b] = o[b];
    __syncthreads();
    int s = c * chunkE;
    int e = min(s + chunkE, E);
    for (int j = s + (int)threadIdx.x; j < e; j += 256) {
        int r = rows[j];
        int pos = atomicAdd(&cur[r >> BSHIFT], 1);
        edges[pos] = make_int2(((r & BMASK) << 17) | cols[j],
                               __float_as_int(vals[j]));
    }
}

// spmm: one wave per 16-row bucket; wave-private LDS tile acc[16][64] fp32;
// per edge ds_add_f32 (lane d -> 2 lanes/bank, conflict-free); scalar edge
// stream; 8 independent gathers in flight; bf16 in/out.
__global__ __launch_bounds__(256) void spmm_bkt_k(
    const int* __restrict__ bucket_start, const int2* __restrict__ edges,
    const ushort* __restrict__ x, ushort* __restrict__ y, int nbucket)
{
    __shared__ float acc[4][16][64];   // 16KB; wave-private slices, no syncs
    int wid = __builtin_amdgcn_readfirstlane((int)(threadIdx.x >> 6));
    int bk = blockIdx.x * 4 + wid;
    if (bk >= nbucket) return;
    int d = (int)(threadIdx.x & 63);
    float (*a)[64] = acc[wid];
    #pragma unroll
    for (int r = 0; r < 16; ++r) a[r][d] = 0.f;

    int s = bucket_start[bk];      // wave-uniform -> s_load
    int e = bucket_start[bk + 1];
    int j = s;
    for (; j + 8 <= e; j += 8) {
        int2 e0 = edges[j];
        int2 e1 = edges[j + 1];
        int2 e2 = edges[j + 2];
        int2 e3 = edges[j + 3];
        int2 e4 = edges[j + 4];
        int2 e5 = edges[j + 5];
        int2 e6 = edges[j + 6];
        int2 e7 = edges[j + 7];
        float g0 = bf2f(x[(long)(e0.x & 0x1FFFF) * 64 + d]);
        float g1 = bf2f(x[(long)(e1.x & 0x1FFFF) * 64 + d]);
        float g2 = bf2f(x[(long)(e2.x & 0x1FFFF) * 64 + d]);
        float g3 = bf2f(x[(long)(e3.x & 0x1FFFF) * 64 + d]);
        float g4 = bf2f(x[(long)(e4.x & 0x1FFFF) * 64 + d]);
        float g5 = bf2f(x[(long)(e5.x & 0x1FFFF) * 64 + d]);
        float g6 = bf2f(x[(long)(e6.x & 0x1FFFF) * 64 + d]);
        float g7 = bf2f(x[(long)(e7.x & 0x1FFFF) * 64 + d]);
        atomicAdd(&a[(unsigned)e0.x >> 17][d], __int_as_float(e0.y) * g0);
        atomicAdd(&a[(unsigned)e1.x >> 17][d], __int_as_float(e1.y) * g1);
        atomicAdd(&a[(unsigned)e2.x >> 17][d], __int_as_float(e2.y) * g2);
        atomicAdd(&a[(unsigned)e3.x >> 17][d], __int_as_float(e3.y) * g3);
        atomicAdd(&a[(unsigned)e4.x >> 17][d], __int_as_float(e4.y) * g4);
        atomicAdd(&a[(unsigned)e5.x >> 17][d], __int_as_float(e5.y) * g5);
        atomicAdd(&a[(unsigned)e6.x >> 17][d], __int_as_float(e6.y) * g6);
        atomicAdd(&a[(unsigned)e7.x >> 17][d], __int_as_float(e7.y) * g7);
    }
    for (; j < e; ++j) {
        int2 e0 = edges[j];
        float g0 = bf2f(x[(long)(e0.x & 0x1FFFF) * 64 + d]);
        atomicAdd(&a[(unsigned)e0.x >> 17][d], __int_as_float(e0.y) * g0);
    }
    // drain (wave-private -> no barrier needed); coalesced 128B bf16 rows
    #pragma unroll
    for (int r = 0; r < 16; ++r)
        y[((long)bk * 16 + r) * 64 + d] = f2bf(a[r][d]);
}

// out[0..2] = 0.25*emb[idx] (hop-0 term), out[3..5] = emb[idx]; float4 lanes
__global__ __launch_bounds__(256) void init_out_k(
    const float* __restrict__ emb, const int* __restrict__ n0,
    const int* __restrict__ n1, const int* __restrict__ n2,
    float* __restrict__ out, int B)
{
    int tid = blockIdx.x * blockDim.x + threadIdx.x;
    int total = 3 * B * 16;                 // float4 granularity
    if (tid >= total) return;
    int arr = tid / (B * 16);
    int rem = tid - arr * (B * 16);
    int b = rem >> 4;
    int d4 = rem & 15;
    const int* __restrict__ idx = (arr == 0) ? n0 : ((arr == 1) ? n1 : n2);
    float4 v = *(const float4*)(emb + (long)idx[b] * 64 + d4 * 4);
    float4 q = make_float4(0.25f * v.x, 0.25f * v.y, 0.25f * v.z, 0.25f * v.w);
    *(float4*)(out + (long)arr * B * 64 + (long)rem * 4) = q;
    *(float4*)(out + (long)(arr + 3) * B * 64 + (long)rem * 4) = v;
}

// pooled += 0.25 * agg_bf16[idx]
__global__ __launch_bounds__(256) void gather_add_k(
    const ushort* __restrict__ agg, const int* __restrict__ n0,
    const int* __restrict__ n1, const int* __restrict__ n2,
    float* __restrict__ out, int B)
{
    int tid = blockIdx.x * blockDim.x + threadIdx.x;
    int total = 3 * B * 16;
    if (tid >= total) return;
    int arr = tid / (B * 16);
    int rem = tid - arr * (B * 16);
    int b = rem >> 4;
    int d4 = rem & 15;
    const int* __restrict__ idx = (arr == 0) ? n0 : ((arr == 1) ? n1 : n2);
    ushort4 v = *(const ushort4*)(agg + (long)idx[b] * 64 + d4 * 4);
    float* o = out + (long)arr * B * 64 + (long)rem * 4;
    float4 cur = *(float4*)o;
    cur.x += 0.25f * bf2f(v.x); cur.y += 0.25f * bf2f(v.y);
    cur.z += 0.25f * bf2f(v.z); cur.w += 0.25f * bf2f(v.w);
    *(float4*)o = cur;
}

extern "C" void kernel_launch(void* const* d_in, const int* in_sizes, int n_in,
                              void* d_out, int out_size, void* d_ws, size_t ws_size,
                              hipStream_t stream)
{
    const float* emb  = (const float*)d_in[0];
    const int*   rows = (const int*)d_in[1];
    const int*   cols = (const int*)d_in[2];
    const float* vals = (const float*)d_in[3];
    const int*   node = (const int*)d_in[4];
    const int*   pos  = (const int*)d_in[5];
    const int*   neg  = (const int*)d_in[6];
    float* out = (float*)d_out;

    const int E = in_sizes[1];
    const int B = in_sizes[4];
    const int N = in_sizes[0] / 64;
    const size_t nd = (size_t)N * 64;
    const int chunkE = (E + NCHUNK - 1) / NCHUNK;
    const int nbucket = (N + BMASK) >> BSHIFT;     // 6250 for N=100000

    // workspace layout
    ushort* aggA        = (ushort*)d_ws;            // N*64 bf16
    ushort* aggB        = aggA + nd;                // N*64 bf16
    ushort* x0          = aggB + nd;                // N*64 bf16 (emb cast)
    int2*  edges        = (int2*)(x0 + nd);         // E
    int*   cnt          = (int*)(edges + E);        // NCHUNK * NBUCKET
    int*   totals       = cnt + (long)NCHUNK * NBUCKET;  // NBUCKET
    int*   bucket_start = totals + NBUCKET;         // NBUCKET+1
    int*   bsums        = bucket_start + NBUCKET + 1;    // <=25
    int*   bprefix      = bsums + 32;               // <=25

    const int gtotal   = 3 * B * 16;
    const int gblocks  = (gtotal + 255) / 256;
    const int cblocks  = ((int)(nd / 4) + 255) / 256;
    const int bblocks  = (nbucket + 255) / 256;     // 25
    const int sblocks  = (nbucket + 3) / 4;         // spmm: 4 buckets/block

    init_out_k<<<gblocks, 256, 0, stream>>>(emb, node, pos, neg, out, B);
    f2bf_k<<<cblocks, 256, 0, stream>>>(emb, x0, (int)(nd / 4));

    // ---- bucketed partition, zero global atomics ----
    count_k<<<NCHUNK, 256, 0, stream>>>(rows, cnt, E, chunkE);
    totals_k<<<bblocks, 256, 0, stream>>>(cnt, totals, NCHUNK);
    block_sums_k<<<bblocks, 256, 0, stream>>>(totals, bsums, nbucket);
    scan_bsums_k<<<1, 512, 0, stream>>>(bsums, bprefix, bblocks);
    scan_counts_k<<<bblocks, 256, 0, stream>>>(totals, bprefix, bucket_start, nbucket);
    offs_k<<<bblocks, 256, 0, stream>>>(cnt, bucket_start, NCHUNK);
    scatter3_k<<<NCHUNK, 256, 0, stream>>>(rows, cols, vals, cnt, edges, E, chunkE);

    // ---- 3 propagation hops ----
    spmm_bkt_k<<<sblocks, 256, 0, stream>>>(bucket_start, edges, x0, aggA, nbucket);
    gather_add_k<<<gblocks, 256, 0, stream>>>(aggA, node, pos, neg, out, B);

    spmm_bkt_k<<<sblocks, 256, 0, stream>>>(bucket_start, edges, aggA, aggB, nbucket);
    gather_add_k<<<gblocks, 256, 0, stream>>>(aggB, node, pos, neg, out, B);

    spmm_bkt_k<<<sblocks, 256, 0, stream>>>(bucket_start, edges, aggB, aggA, nbucket);
    gather_add_k<<<gblocks, 256, 0, stream>>>(aggA, node, pos, neg, out, B);
}

// Round 7
// 387.655 us; speedup vs baseline: 4.9345x; 4.9345x over previous
//
#include <hip/hip_runtime.h>

// LightGCN 3-hop propagation, D=64, bf16 features / fp32 accumulate.
// R7: R6 post-mortem — LDS-atomic accumulate serialized the gather loop
// (VGPR dropped to 12, ~900cy/edge). Fix: REGISTER accumulation. The
// bucket-local row of an edge is wave-uniform (wave processes one edge,
// lane = feature dim), so accumulator dispatch is a SCALAR 16-way switch
// (SALU, runs parallel to VALU, hidden under vmem latency). Partition
// passes A-C (LDS-only, no global atomics) kept from R6 — they replace
// R5's hist_rank (68us atomic wall) + memset + rank array.

#define NBUCKET 6250     // N=100000 rows, 16 per bucket
#define BSHIFT  4
#define BMASK   15
#define NCHUNK  256      // edge chunks; E=1.6M -> 6250 edges/chunk

static __device__ __forceinline__ ushort f2bf(float f) {
    unsigned u = __float_as_uint(f);
    unsigned r = (u + 0x7fffu + ((u >> 16) & 1u)) >> 16;   // RNE
    return (ushort)r;
}
static __device__ __forceinline__ float bf2f(ushort b) {
    return __uint_as_float(((unsigned)b) << 16);
}

__global__ __launch_bounds__(256) void f2bf_k(
    const float* __restrict__ in, ushort* __restrict__ out, int n4)
{
    int i = blockIdx.x * blockDim.x + threadIdx.x;
    if (i >= n4) return;
    float4 v = *(const float4*)(in + (long)i * 4);
    ushort4 o;
    o.x = f2bf(v.x); o.y = f2bf(v.y); o.z = f2bf(v.z); o.w = f2bf(v.w);
    *(ushort4*)(out + (long)i * 4) = o;
}

// pass A: per-chunk bucket histogram in LDS (no global atomics)
__global__ __launch_bounds__(256) void count_k(
    const int* __restrict__ rows, int* __restrict__ cnt, int E, int chunkE)
{
    __shared__ unsigned h[NBUCKET];
    int c = blockIdx.x;
    for (int b = threadIdx.x; b < NBUCKET; b += 256) h[b] = 0u;
    __syncthreads();
    int s = c * chunkE;
    int e = min(s + chunkE, E);
    for (int j = s + (int)threadIdx.x; j < e; j += 256)
        atomicAdd(&h[rows[j] >> BSHIFT], 1u);
    __syncthreads();
    int* o = cnt + (long)c * NBUCKET;
    for (int b = threadIdx.x; b < NBUCKET; b += 256) o[b] = (int)h[b];
}

// pass B1: totals[b] = sum_c cnt[c][b]   (coalesced across bucket axis)
__global__ __launch_bounds__(256) void totals_k(
    const int* __restrict__ cnt, int* __restrict__ totals, int nchunk)
{
    int b = blockIdx.x * 256 + threadIdx.x;
    if (b >= NBUCKET) return;
    int t = 0;
    for (int c = 0; c < nchunk; ++c) t += cnt[(long)c * NBUCKET + b];
    totals[b] = t;
}

__global__ __launch_bounds__(256) void block_sums_k(
    const int* __restrict__ counts, int* __restrict__ bsums, int N)
{
    __shared__ int sm[256];
    int i = blockIdx.x * 256 + threadIdx.x;
    sm[threadIdx.x] = (i < N) ? counts[i] : 0;
    __syncthreads();
    for (int off = 128; off > 0; off >>= 1) {
        if (threadIdx.x < off) sm[threadIdx.x] += sm[threadIdx.x + off];
        __syncthreads();
    }
    if (threadIdx.x == 0) bsums[blockIdx.x] = sm[0];
}

__global__ __launch_bounds__(512) void scan_bsums_k(
    const int* __restrict__ bsums, int* __restrict__ bprefix, int nb)
{
    __shared__ int sm[512];
    int t = threadIdx.x;
    int v = (t < nb) ? bsums[t] : 0;
    sm[t] = v;
    __syncthreads();
    for (int off = 1; off < 512; off <<= 1) {
        int add = (t >= off) ? sm[t - off] : 0;
        __syncthreads();
        sm[t] += add;
        __syncthreads();
    }
    if (t < nb) bprefix[t] = sm[t] - v;   // exclusive prefix of block sums
}

__global__ __launch_bounds__(256) void scan_counts_k(
    const int* __restrict__ counts, const int* __restrict__ bprefix,
    int* __restrict__ bucket_start, int N)
{
    __shared__ int sm[256];
    int i = blockIdx.x * 256 + threadIdx.x;
    int c = (i < N) ? counts[i] : 0;
    sm[threadIdx.x] = c;
    __syncthreads();
    for (int off = 1; off < 256; off <<= 1) {
        int add = (threadIdx.x >= off) ? sm[threadIdx.x - off] : 0;
        __syncthreads();
        sm[threadIdx.x] += add;
        __syncthreads();
    }
    if (i < N) {
        int excl = sm[threadIdx.x] - c + bprefix[blockIdx.x];
        bucket_start[i] = excl;
        if (i == N - 1) bucket_start[N] = excl + c;   // == E
    }
}

// pass B2: cnt[c][b] <- global base offset for (chunk c, bucket b), in place
__global__ __launch_bounds__(256) void offs_k(
    int* __restrict__ cnt, const int* __restrict__ bucket_start, int nchunk)
{
    int b = blockIdx.x * 256 + threadIdx.x;
    if (b >= NBUCKET) return;
    int base = bucket_start[b];
    for (int c = 0; c < nchunk; ++c) {
        long i = (long)c * NBUCKET + b;
        int v = cnt[i];
        cnt[i] = base;
        base += v;
    }
}

// pass C: partition edges into bucket segments; LDS cursors only.
// edge payload: .x = (row&15)<<17 | col  (col < 2^17), .y = val bits
__global__ __launch_bounds__(256) void scatter3_k(
    const int* __restrict__ rows, const int* __restrict__ cols,
    const float* __restrict__ vals, const int* __restrict__ offs,
    int2* __restrict__ edges, int E, int chunkE)
{
    __shared__ int cur[NBUCKET];
    int c = blockIdx.x;
    const int* o = offs + (long)c * NBUCKET;
    for (int b = threadIdx.x; b < NBUCKET; b += 256) cur[b] = o[b];
    __syncthreads();
    int s = c * chunkE;
    int e = min(s + chunkE, E);
    for (int j = s + (int)threadIdx.x; j < e; j += 256) {
        int r = rows[j];
        int pos = atomicAdd(&cur[r >> BSHIFT], 1);
        edges[pos] = make_int2(((r & BMASK) << 17) | cols[j],
                               __float_as_int(vals[j]));
    }
}

// scalar 16-way accumulator dispatch: rl is wave-uniform -> SALU branch
#define ACC(rl, p) switch (rl) { \
    case 0:  a0  += (p); break; case 1:  a1  += (p); break; \
    case 2:  a2  += (p); break; case 3:  a3  += (p); break; \
    case 4:  a4  += (p); break; case 5:  a5  += (p); break; \
    case 6:  a6  += (p); break; case 7:  a7  += (p); break; \
    case 8:  a8  += (p); break; case 9:  a9  += (p); break; \
    case 10: a10 += (p); break; case 11: a11 += (p); break; \
    case 12: a12 += (p); break; case 13: a13 += (p); break; \
    case 14: a14 += (p); break; default: a15 += (p); break; }

// spmm: one wave per 16-row bucket; 16 fp32 register accumulators per lane;
// batched 8-gather loads then 8 scalar-switch accumulates; bf16 in/out.
__global__ __launch_bounds__(256) void spmm_bkt_k(
    const int* __restrict__ bucket_start, const int2* __restrict__ edges,
    const ushort* __restrict__ x, ushort* __restrict__ y, int nbucket, int N)
{
    int wid = __builtin_amdgcn_readfirstlane((int)(threadIdx.x >> 6));
    int bk = blockIdx.x * 4 + wid;
    if (bk >= nbucket) return;
    int d = (int)(threadIdx.x & 63);
    float a0 = 0.f, a1 = 0.f, a2 = 0.f, a3 = 0.f;
    float a4 = 0.f, a5 = 0.f, a6 = 0.f, a7 = 0.f;
    float a8 = 0.f, a9 = 0.f, a10 = 0.f, a11 = 0.f;
    float a12 = 0.f, a13 = 0.f, a14 = 0.f, a15 = 0.f;

    int s = bucket_start[bk];      // wave-uniform -> s_load
    int e = bucket_start[bk + 1];
    int j = s;
    for (; j + 8 <= e; j += 8) {
        int2 e0 = edges[j];
        int2 e1 = edges[j + 1];
        int2 e2 = edges[j + 2];
        int2 e3 = edges[j + 3];
        int2 e4 = edges[j + 4];
        int2 e5 = edges[j + 5];
        int2 e6 = edges[j + 6];
        int2 e7 = edges[j + 7];
        float p0 = __int_as_float(e0.y) * bf2f(x[(long)(e0.x & 0x1FFFF) * 64 + d]);
        float p1 = __int_as_float(e1.y) * bf2f(x[(long)(e1.x & 0x1FFFF) * 64 + d]);
        float p2 = __int_as_float(e2.y) * bf2f(x[(long)(e2.x & 0x1FFFF) * 64 + d]);
        float p3 = __int_as_float(e3.y) * bf2f(x[(long)(e3.x & 0x1FFFF) * 64 + d]);
        float p4 = __int_as_float(e4.y) * bf2f(x[(long)(e4.x & 0x1FFFF) * 64 + d]);
        float p5 = __int_as_float(e5.y) * bf2f(x[(long)(e5.x & 0x1FFFF) * 64 + d]);
        float p6 = __int_as_float(e6.y) * bf2f(x[(long)(e6.x & 0x1FFFF) * 64 + d]);
        float p7 = __int_as_float(e7.y) * bf2f(x[(long)(e7.x & 0x1FFFF) * 64 + d]);
        ACC((unsigned)e0.x >> 17, p0);
        ACC((unsigned)e1.x >> 17, p1);
        ACC((unsigned)e2.x >> 17, p2);
        ACC((unsigned)e3.x >> 17, p3);
        ACC((unsigned)e4.x >> 17, p4);
        ACC((unsigned)e5.x >> 17, p5);
        ACC((unsigned)e6.x >> 17, p6);
        ACC((unsigned)e7.x >> 17, p7);
    }
    for (; j < e; ++j) {
        int2 e0 = edges[j];
        float p0 = __int_as_float(e0.y) * bf2f(x[(long)(e0.x & 0x1FFFF) * 64 + d]);
        ACC((unsigned)e0.x >> 17, p0);
    }
    // drain: 16 coalesced 128B bf16 row stores
    long rbase = (long)bk * 16;
    if (rbase + 16 <= N) {
        y[(rbase + 0)  * 64 + d] = f2bf(a0);
        y[(rbase + 1)  * 64 + d] = f2bf(a1);
        y[(rbase + 2)  * 64 + d] = f2bf(a2);
        y[(rbase + 3)  * 64 + d] = f2bf(a3);
        y[(rbase + 4)  * 64 + d] = f2bf(a4);
        y[(rbase + 5)  * 64 + d] = f2bf(a5);
        y[(rbase + 6)  * 64 + d] = f2bf(a6);
        y[(rbase + 7)  * 64 + d] = f2bf(a7);
        y[(rbase + 8)  * 64 + d] = f2bf(a8);
        y[(rbase + 9)  * 64 + d] = f2bf(a9);
        y[(rbase + 10) * 64 + d] = f2bf(a10);
        y[(rbase + 11) * 64 + d] = f2bf(a11);
        y[(rbase + 12) * 64 + d] = f2bf(a12);
        y[(rbase + 13) * 64 + d] = f2bf(a13);
        y[(rbase + 14) * 64 + d] = f2bf(a14);
        y[(rbase + 15) * 64 + d] = f2bf(a15);
    } else {
        float aa[16] = {a0,a1,a2,a3,a4,a5,a6,a7,a8,a9,a10,a11,a12,a13,a14,a15};
        #pragma unroll
        for (int r = 0; r < 16; ++r)
            if (rbase + r < N) y[(rbase + r) * 64 + d] = f2bf(aa[r]);
    }
}

// out[0..2] = 0.25*emb[idx] (hop-0 term), out[3..5] = emb[idx]; float4 lanes
__global__ __launch_bounds__(256) void init_out_k(
    const float* __restrict__ emb, const int* __restrict__ n0,
    const int* __restrict__ n1, const int* __restrict__ n2,
    float* __restrict__ out, int B)
{
    int tid = blockIdx.x * blockDim.x + threadIdx.x;
    int total = 3 * B * 16;                 // float4 granularity
    if (tid >= total) return;
    int arr = tid / (B * 16);
    int rem = tid - arr * (B * 16);
    int b = rem >> 4;
    int d4 = rem & 15;
    const int* __restrict__ idx = (arr == 0) ? n0 : ((arr == 1) ? n1 : n2);
    float4 v = *(const float4*)(emb + (long)idx[b] * 64 + d4 * 4);
    float4 q = make_float4(0.25f * v.x, 0.25f * v.y, 0.25f * v.z, 0.25f * v.w);
    *(float4*)(out + (long)arr * B * 64 + (long)rem * 4) = q;
    *(float4*)(out + (long)(arr + 3) * B * 64 + (long)rem * 4) = v;
}

// pooled += 0.25 * agg_bf16[idx]
__global__ __launch_bounds__(256) void gather_add_k(
    const ushort* __restrict__ agg, const int* __restrict__ n0,
    const int* __restrict__ n1, const int* __restrict__ n2,
    float* __restrict__ out, int B)
{
    int tid = blockIdx.x * blockDim.x + threadIdx.x;
    int total = 3 * B * 16;
    if (tid >= total) return;
    int arr = tid / (B * 16);
    int rem = tid - arr * (B * 16);
    int b = rem >> 4;
    int d4 = rem & 15;
    const int* __restrict__ idx = (arr == 0) ? n0 : ((arr == 1) ? n1 : n2);
    ushort4 v = *(const ushort4*)(agg + (long)idx[b] * 64 + d4 * 4);
    float* o = out + (long)arr * B * 64 + (long)rem * 4;
    float4 cur = *(float4*)o;
    cur.x += 0.25f * bf2f(v.x); cur.y += 0.25f * bf2f(v.y);
    cur.z += 0.25f * bf2f(v.z); cur.w += 0.25f * bf2f(v.w);
    *(float4*)o = cur;
}

extern "C" void kernel_launch(void* const* d_in, const int* in_sizes, int n_in,
                              void* d_out, int out_size, void* d_ws, size_t ws_size,
                              hipStream_t stream)
{
    const float* emb  = (const float*)d_in[0];
    const int*   rows = (const int*)d_in[1];
    const int*   cols = (const int*)d_in[2];
    const float* vals = (const float*)d_in[3];
    const int*   node = (const int*)d_in[4];
    const int*   pos  = (const int*)d_in[5];
    const int*   neg  = (const int*)d_in[6];
    float* out = (float*)d_out;

    const int E = in_sizes[1];
    const int B = in_sizes[4];
    const int N = in_sizes[0] / 64;
    const size_t nd = (size_t)N * 64;
    const int chunkE = (E + NCHUNK - 1) / NCHUNK;
    const int nbucket = (N + BMASK) >> BSHIFT;     // 6250 for N=100000

    // workspace layout
    ushort* aggA        = (ushort*)d_ws;            // N*64 bf16
    ushort* aggB        = aggA + nd;                // N*64 bf16
    ushort* x0          = aggB + nd;                // N*64 bf16 (emb cast)
    int2*  edges        = (int2*)(x0 + nd);         // E
    int*   cnt          = (int*)(edges + E);        // NCHUNK * NBUCKET
    int*   totals       = cnt + (long)NCHUNK * NBUCKET;  // NBUCKET
    int*   bucket_start = totals + NBUCKET;         // NBUCKET+1
    int*   bsums        = bucket_start + NBUCKET + 1;    // <=32
    int*   bprefix      = bsums + 32;               // <=32

    const int gtotal   = 3 * B * 16;
    const int gblocks  = (gtotal + 255) / 256;
    const int cblocks  = ((int)(nd / 4) + 255) / 256;
    const int bblocks  = (nbucket + 255) / 256;     // 25
    const int sblocks  = (nbucket + 3) / 4;         // spmm: 4 buckets/block

    init_out_k<<<gblocks, 256, 0, stream>>>(emb, node, pos, neg, out, B);
    f2bf_k<<<cblocks, 256, 0, stream>>>(emb, x0, (int)(nd / 4));

    // ---- bucketed partition, zero global atomics ----
    count_k<<<NCHUNK, 256, 0, stream>>>(rows, cnt, E, chunkE);
    totals_k<<<bblocks, 256, 0, stream>>>(cnt, totals, NCHUNK);
    block_sums_k<<<bblocks, 256, 0, stream>>>(totals, bsums, nbucket);
    scan_bsums_k<<<1, 512, 0, stream>>>(bsums, bprefix, bblocks);
    scan_counts_k<<<bblocks, 256, 0, stream>>>(totals, bprefix, bucket_start, nbucket);
    offs_k<<<bblocks, 256, 0, stream>>>(cnt, bucket_start, NCHUNK);
    scatter3_k<<<NCHUNK, 256, 0, stream>>>(rows, cols, vals, cnt, edges, E, chunkE);

    // ---- 3 propagation hops, register-accumulating spmm ----
    spmm_bkt_k<<<sblocks, 256, 0, stream>>>(bucket_start, edges, x0, aggA, nbucket, N);
    gather_add_k<<<gblocks, 256, 0, stream>>>(aggA, node, pos, neg, out, B);

    spmm_bkt_k<<<sblocks, 256, 0, stream>>>(bucket_start, edges, aggA, aggB, nbucket, N);
    gather_add_k<<<gblocks, 256, 0, stream>>>(aggB, node, pos, neg, out, B);

    spmm_bkt_k<<<sblocks, 256, 0, stream>>>(bucket_start, edges, aggB, aggA, nbucket, N);
    gather_add_k<<<gblocks, 256, 0, stream>>>(aggA, node, pos, neg, out, B);
}

// Round 8
// 273.586 us; speedup vs baseline: 6.9919x; 1.4169x over previous
//
#include <hip/hip_runtime.h>

// LightGCN 3-hop propagation, D=64, bf16 features / fp32 accumulate.
// R8: R7 post-mortem — the 16-way switch accumulator collapsed the spmm's
// MLP (VGPR 20, 90us). Fix: restore the PROVEN row-wave spmm (R4/R5 form:
// one wave per row, lane = dim, 8 static register chains) and make the
// atomic-free bucket partition feed it via pass D: per-bucket LDS counting
// sort (16 cursors/wave, intra-wave ordered) -> exact row-sorted edges +
// row_start. Build has ZERO global atomics. Scans fused into one kernel.

#define NBUCKET 6250     // N=100000 rows, 16 per bucket
#define BSHIFT  4
#define BMASK   15
#define NCHUNK  256      // edge chunks; E=1.6M -> 6250 edges/chunk

static __device__ __forceinline__ ushort f2bf(float f) {
    unsigned u = __float_as_uint(f);
    unsigned r = (u + 0x7fffu + ((u >> 16) & 1u)) >> 16;   // RNE
    return (ushort)r;
}
static __device__ __forceinline__ float bf2f(ushort b) {
    return __uint_as_float(((unsigned)b) << 16);
}

__global__ __launch_bounds__(256) void f2bf_k(
    const float* __restrict__ in, ushort* __restrict__ out, int n4)
{
    int i = blockIdx.x * blockDim.x + threadIdx.x;
    if (i >= n4) return;
    float4 v = *(const float4*)(in + (long)i * 4);
    ushort4 o;
    o.x = f2bf(v.x); o.y = f2bf(v.y); o.z = f2bf(v.z); o.w = f2bf(v.w);
    *(ushort4*)(out + (long)i * 4) = o;
}

// pass A: per-chunk bucket histogram in LDS (no global atomics)
__global__ __launch_bounds__(256) void count_k(
    const int* __restrict__ rows, int* __restrict__ cnt, int E, int chunkE)
{
    __shared__ unsigned h[NBUCKET];
    int c = blockIdx.x;
    for (int b = threadIdx.x; b < NBUCKET; b += 256) h[b] = 0u;
    __syncthreads();
    int s = c * chunkE;
    int e = min(s + chunkE, E);
    for (int j = s + (int)threadIdx.x; j < e; j += 256)
        atomicAdd(&h[rows[j] >> BSHIFT], 1u);
    __syncthreads();
    int* o = cnt + (long)c * NBUCKET;
    for (int b = threadIdx.x; b < NBUCKET; b += 256) o[b] = (int)h[b];
}

// pass B1: totals[b] = sum_c cnt[c][b]   (coalesced across bucket axis)
__global__ __launch_bounds__(256) void totals_k(
    const int* __restrict__ cnt, int* __restrict__ totals, int nchunk)
{
    int b = blockIdx.x * 256 + threadIdx.x;
    if (b >= NBUCKET) return;
    int t = 0;
    for (int c = 0; c < nchunk; ++c) t += cnt[(long)c * NBUCKET + b];
    totals[b] = t;
}

// fused exclusive scan over nbucket elements; single block of 1024
__global__ __launch_bounds__(1024) void scan_fused_k(
    const int* __restrict__ totals, int* __restrict__ bucket_start, int nbucket)
{
    __shared__ int sm[1024];
    __shared__ int carry_s;
    if (threadIdx.x == 0) carry_s = 0;
    __syncthreads();
    int ntile = (nbucket + 1023) / 1024;
    for (int t = 0; t < ntile; ++t) {
        int i = t * 1024 + threadIdx.x;
        int v = (i < nbucket) ? totals[i] : 0;
        sm[threadIdx.x] = v;
        __syncthreads();
        for (int off = 1; off < 1024; off <<= 1) {
            int add = (threadIdx.x >= off) ? sm[threadIdx.x - off] : 0;
            __syncthreads();
            sm[threadIdx.x] += add;
            __syncthreads();
        }
        int c0 = carry_s;
        if (i < nbucket) bucket_start[i] = c0 + sm[threadIdx.x] - v;
        __syncthreads();
        if (threadIdx.x == 1023) carry_s = c0 + sm[1023];
        __syncthreads();
    }
    if (threadIdx.x == 0) bucket_start[nbucket] = carry_s;   // == E
}

// pass B2: cnt[c][b] <- global base offset for (chunk c, bucket b), in place
__global__ __launch_bounds__(256) void offs_k(
    int* __restrict__ cnt, const int* __restrict__ bucket_start, int nchunk)
{
    int b = blockIdx.x * 256 + threadIdx.x;
    if (b >= NBUCKET) return;
    int base = bucket_start[b];
    for (int c = 0; c < nchunk; ++c) {
        long i = (long)c * NBUCKET + b;
        int v = cnt[i];
        cnt[i] = base;
        base += v;
    }
}

// pass C: partition edges into bucket segments; LDS cursors only.
// edge payload: .x = (row&15)<<17 | col  (col < 2^17), .y = val bits
__global__ __launch_bounds__(256) void scatter3_k(
    const int* __restrict__ rows, const int* __restrict__ cols,
    const float* __restrict__ vals, const int* __restrict__ offs,
    int2* __restrict__ edges, int E, int chunkE)
{
    __shared__ int cur[NBUCKET];
    int c = blockIdx.x;
    const int* o = offs + (long)c * NBUCKET;
    for (int b = threadIdx.x; b < NBUCKET; b += 256) cur[b] = o[b];
    __syncthreads();
    int s = c * chunkE;
    int e = min(s + chunkE, E);
    for (int j = s + (int)threadIdx.x; j < e; j += 256) {
        int r = rows[j];
        int pos = atomicAdd(&cur[r >> BSHIFT], 1);
        edges[pos] = make_int2(((r & BMASK) << 17) | cols[j],
                               __float_as_int(vals[j]));
    }
}

// pass D: per-bucket LDS counting sort over the 16 row-locals.
// One wave per bucket; 16 LDS cursors/wave; intra-wave program order makes
// the count -> prefix -> scatter sequence safe without barriers.
// Produces exact row-sorted edges2 and row_start[N+1].
__global__ __launch_bounds__(256) void sort_bkt_k(
    const int* __restrict__ bucket_start, const int2* __restrict__ edges_in,
    int2* __restrict__ edges_out, int* __restrict__ row_start, int nbucket)
{
    __shared__ int cur[4][16];
    int w = (int)(threadIdx.x >> 6);
    int lane = (int)(threadIdx.x & 63);
    int bk = blockIdx.x * 4 + w;
    if (bk >= nbucket) return;
    int s = bucket_start[bk];
    int e = bucket_start[bk + 1];
    if (lane < 16) cur[w][lane] = 0;
    for (int j = s + lane; j < e; j += 64)
        atomicAdd(&cur[w][(unsigned)edges_in[j].x >> 17], 1);
    if (lane == 0) {
        int run = s;
        #pragma unroll
        for (int r = 0; r < 16; ++r) {
            int c = cur[w][r];
            cur[w][r] = run;
            row_start[bk * 16 + r] = run;
            run += c;
        }
    }
    for (int j = s + lane; j < e; j += 64) {
        int2 ed = edges_in[j];
        int pos = atomicAdd(&cur[w][(unsigned)ed.x >> 17], 1);
        edges_out[pos] = ed;
    }
    if (bk == nbucket - 1 && lane == 0) row_start[nbucket * 16] = e;  // == E
}

// spmm: one wave per row; lane = feature dim; scalar edge stream;
// 8 independent gather chains; bf16 in/out, fp32 accumulate. (R5 form.)
__global__ __launch_bounds__(256) void spmm_csr_k(
    const int* __restrict__ row_start, const int2* __restrict__ edges,
    const ushort* __restrict__ x, ushort* __restrict__ y, int N)
{
    int wid = __builtin_amdgcn_readfirstlane((int)(threadIdx.x >> 6));
    int r = blockIdx.x * 4 + wid;
    if (r >= N) return;
    int d = (int)(threadIdx.x & 63);
    int s = row_start[r];      // wave-uniform -> s_load
    int e = row_start[r + 1];
    float a0 = 0.f, a1 = 0.f, a2 = 0.f, a3 = 0.f;
    float a4 = 0.f, a5 = 0.f, a6 = 0.f, a7 = 0.f;
    int j = s;
    for (; j + 8 <= e; j += 8) {
        int2 e0 = edges[j];
        int2 e1 = edges[j + 1];
        int2 e2 = edges[j + 2];
        int2 e3 = edges[j + 3];
        int2 e4 = edges[j + 4];
        int2 e5 = edges[j + 5];
        int2 e6 = edges[j + 6];
        int2 e7 = edges[j + 7];
        a0 += __int_as_float(e0.y) * bf2f(x[(long)(e0.x & 0x1FFFF) * 64 + d]);
        a1 += __int_as_float(e1.y) * bf2f(x[(long)(e1.x & 0x1FFFF) * 64 + d]);
        a2 += __int_as_float(e2.y) * bf2f(x[(long)(e2.x & 0x1FFFF) * 64 + d]);
        a3 += __int_as_float(e3.y) * bf2f(x[(long)(e3.x & 0x1FFFF) * 64 + d]);
        a4 += __int_as_float(e4.y) * bf2f(x[(long)(e4.x & 0x1FFFF) * 64 + d]);
        a5 += __int_as_float(e5.y) * bf2f(x[(long)(e5.x & 0x1FFFF) * 64 + d]);
        a6 += __int_as_float(e6.y) * bf2f(x[(long)(e6.x & 0x1FFFF) * 64 + d]);
        a7 += __int_as_float(e7.y) * bf2f(x[(long)(e7.x & 0x1FFFF) * 64 + d]);
    }
    for (; j + 4 <= e; j += 4) {
        int2 e0 = edges[j];
        int2 e1 = edges[j + 1];
        int2 e2 = edges[j + 2];
        int2 e3 = edges[j + 3];
        a0 += __int_as_float(e0.y) * bf2f(x[(long)(e0.x & 0x1FFFF) * 64 + d]);
        a1 += __int_as_float(e1.y) * bf2f(x[(long)(e1.x & 0x1FFFF) * 64 + d]);
        a2 += __int_as_float(e2.y) * bf2f(x[(long)(e2.x & 0x1FFFF) * 64 + d]);
        a3 += __int_as_float(e3.y) * bf2f(x[(long)(e3.x & 0x1FFFF) * 64 + d]);
    }
    for (; j < e; ++j) {
        int2 e0 = edges[j];
        a0 += __int_as_float(e0.y) * bf2f(x[(long)(e0.x & 0x1FFFF) * 64 + d]);
    }
    float sum = ((a0 + a1) + (a2 + a3)) + ((a4 + a5) + (a6 + a7));
    y[(long)r * 64 + d] = f2bf(sum);
}

// out[0..2] = 0.25*emb[idx] (hop-0 term), out[3..5] = emb[idx]; float4 lanes
__global__ __launch_bounds__(256) void init_out_k(
    const float* __restrict__ emb, const int* __restrict__ n0,
    const int* __restrict__ n1, const int* __restrict__ n2,
    float* __restrict__ out, int B)
{
    int tid = blockIdx.x * blockDim.x + threadIdx.x;
    int total = 3 * B * 16;                 // float4 granularity
    if (tid >= total) return;
    int arr = tid / (B * 16);
    int rem = tid - arr * (B * 16);
    int b = rem >> 4;
    int d4 = rem & 15;
    const int* __restrict__ idx = (arr == 0) ? n0 : ((arr == 1) ? n1 : n2);
    float4 v = *(const float4*)(emb + (long)idx[b] * 64 + d4 * 4);
    float4 q = make_float4(0.25f * v.x, 0.25f * v.y, 0.25f * v.z, 0.25f * v.w);
    *(float4*)(out + (long)arr * B * 64 + (long)rem * 4) = q;
    *(float4*)(out + (long)(arr + 3) * B * 64 + (long)rem * 4) = v;
}

// pooled += 0.25 * agg_bf16[idx]
__global__ __launch_bounds__(256) void gather_add_k(
    const ushort* __restrict__ agg, const int* __restrict__ n0,
    const int* __restrict__ n1, const int* __restrict__ n2,
    float* __restrict__ out, int B)
{
    int tid = blockIdx.x * blockDim.x + threadIdx.x;
    int total = 3 * B * 16;
    if (tid >= total) return;
    int arr = tid / (B * 16);
    int rem = tid - arr * (B * 16);
    int b = rem >> 4;
    int d4 = rem & 15;
    const int* __restrict__ idx = (arr == 0) ? n0 : ((arr == 1) ? n1 : n2);
    ushort4 v = *(const ushort4*)(agg + (long)idx[b] * 64 + d4 * 4);
    float* o = out + (long)arr * B * 64 + (long)rem * 4;
    float4 cur = *(float4*)o;
    cur.x += 0.25f * bf2f(v.x); cur.y += 0.25f * bf2f(v.y);
    cur.z += 0.25f * bf2f(v.z); cur.w += 0.25f * bf2f(v.w);
    *(float4*)o = cur;
}

extern "C" void kernel_launch(void* const* d_in, const int* in_sizes, int n_in,
                              void* d_out, int out_size, void* d_ws, size_t ws_size,
                              hipStream_t stream)
{
    const float* emb  = (const float*)d_in[0];
    const int*   rows = (const int*)d_in[1];
    const int*   cols = (const int*)d_in[2];
    const float* vals = (const float*)d_in[3];
    const int*   node = (const int*)d_in[4];
    const int*   pos  = (const int*)d_in[5];
    const int*   neg  = (const int*)d_in[6];
    float* out = (float*)d_out;

    const int E = in_sizes[1];
    const int B = in_sizes[4];
    const int N = in_sizes[0] / 64;
    const size_t nd = (size_t)N * 64;
    const int chunkE = (E + NCHUNK - 1) / NCHUNK;
    const int nbucket = (N + BMASK) >> BSHIFT;     // 6250 for N=100000

    // workspace layout (x0 folded into aggB: layer1 reads aggB)
    ushort* aggA        = (ushort*)d_ws;            // N*64 bf16
    ushort* aggB        = aggA + nd;                // N*64 bf16 (also emb cast)
    int2*  edges        = (int2*)(aggB + nd);       // E (bucket-grouped)
    int2*  edges2       = edges + E;                // E (row-sorted)
    int*   cnt          = (int*)(edges2 + E);       // NCHUNK * NBUCKET
    int*   totals       = cnt + (long)NCHUNK * NBUCKET;  // NBUCKET
    int*   bucket_start = totals + NBUCKET;         // NBUCKET+1
    int*   row_start    = bucket_start + NBUCKET + 1;    // N+1

    const int gtotal   = 3 * B * 16;
    const int gblocks  = (gtotal + 255) / 256;
    const int cblocks  = ((int)(nd / 4) + 255) / 256;
    const int bblocks  = (nbucket + 255) / 256;     // 25
    const int dblocks  = (nbucket + 3) / 4;         // sortD: 4 buckets/block
    const int rblocks  = (N + 3) / 4;               // spmm: 4 rows/block

    init_out_k<<<gblocks, 256, 0, stream>>>(emb, node, pos, neg, out, B);
    f2bf_k<<<cblocks, 256, 0, stream>>>(emb, aggB, (int)(nd / 4));

    // ---- bucketed partition + per-bucket counting sort; no global atomics ----
    count_k<<<NCHUNK, 256, 0, stream>>>(rows, cnt, E, chunkE);
    totals_k<<<bblocks, 256, 0, stream>>>(cnt, totals, NCHUNK);
    scan_fused_k<<<1, 1024, 0, stream>>>(totals, bucket_start, nbucket);
    offs_k<<<bblocks, 256, 0, stream>>>(cnt, bucket_start, NCHUNK);
    scatter3_k<<<NCHUNK, 256, 0, stream>>>(rows, cols, vals, cnt, edges, E, chunkE);
    sort_bkt_k<<<dblocks, 256, 0, stream>>>(bucket_start, edges, edges2, row_start, nbucket);

    // ---- 3 propagation hops, row-wave register-accumulating spmm ----
    spmm_csr_k<<<rblocks, 256, 0, stream>>>(row_start, edges2, aggB, aggA, N);
    gather_add_k<<<gblocks, 256, 0, stream>>>(aggA, node, pos, neg, out, B);

    spmm_csr_k<<<rblocks, 256, 0, stream>>>(row_start, edges2, aggA, aggB, N);
    gather_add_k<<<gblocks, 256, 0, stream>>>(aggB, node, pos, neg, out, B);

    spmm_csr_k<<<rblocks, 256, 0, stream>>>(row_start, edges2, aggB, aggA, N);
    gather_add_k<<<gblocks, 256, 0, stream>>>(aggA, node, pos, neg, out, B);
}

// Round 9
// 225.536 us; speedup vs baseline: 8.4815x; 1.2131x over previous
//
#include <hip/hip_runtime.h>

// LightGCN 3-hop propagation, D=64, bf16 features / fp32 accumulate.
// R9: R8 post-mortem — offs_k was 63us at 1% occupancy because its in-place
// RMW loop (load cnt[i] / store cnt[i] / next load) can't be disambiguated
// by the compiler -> one memory latency per iteration. Fix: localscan_k
// writes the local prefix to a SEPARATE restrict array (loads stream ahead,
// unroll x8) and emits totals[b] as a by-product (kills totals_k's pass).
// bucket_start base folded into scatter3's LDS cursor init. offs reuses
// edges2's storage (dead before sort_bkt overwrites it).

#define NBUCKET 6250     // N=100000 rows, 16 per bucket
#define BSHIFT  4
#define BMASK   15
#define NCHUNK  256      // edge chunks; E=1.6M -> 6250 edges/chunk

static __device__ __forceinline__ ushort f2bf(float f) {
    unsigned u = __float_as_uint(f);
    unsigned r = (u + 0x7fffu + ((u >> 16) & 1u)) >> 16;   // RNE
    return (ushort)r;
}
static __device__ __forceinline__ float bf2f(ushort b) {
    return __uint_as_float(((unsigned)b) << 16);
}

__global__ __launch_bounds__(256) void f2bf_k(
    const float* __restrict__ in, ushort* __restrict__ out, int n4)
{
    int i = blockIdx.x * blockDim.x + threadIdx.x;
    if (i >= n4) return;
    float4 v = *(const float4*)(in + (long)i * 4);
    ushort4 o;
    o.x = f2bf(v.x); o.y = f2bf(v.y); o.z = f2bf(v.z); o.w = f2bf(v.w);
    *(ushort4*)(out + (long)i * 4) = o;
}

// pass A: per-chunk bucket histogram in LDS (no global atomics)
__global__ __launch_bounds__(256) void count_k(
    const int* __restrict__ rows, int* __restrict__ cnt, int E, int chunkE)
{
    __shared__ unsigned h[NBUCKET];
    int c = blockIdx.x;
    for (int b = threadIdx.x; b < NBUCKET; b += 256) h[b] = 0u;
    __syncthreads();
    int s = c * chunkE;
    int e = min(s + chunkE, E);
    for (int j = s + (int)threadIdx.x; j < e; j += 256)
        atomicAdd(&h[rows[j] >> BSHIFT], 1u);
    __syncthreads();
    int* o = cnt + (long)c * NBUCKET;
    for (int b = threadIdx.x; b < NBUCKET; b += 256) o[b] = (int)h[b];
}

// pass B: per-bucket local exclusive prefix over chunks + bucket totals.
// Separate in/out arrays (restrict) so the 256 loads stream ahead of the
// serial add chain.
__global__ __launch_bounds__(256) void localscan_k(
    const int* __restrict__ cnt, int* __restrict__ offs,
    int* __restrict__ totals)
{
    int b = blockIdx.x * 256 + threadIdx.x;
    if (b >= NBUCKET) return;
    int run = 0;
    #pragma unroll 8
    for (int c = 0; c < NCHUNK; ++c) {
        long i = (long)c * NBUCKET + b;
        int v = cnt[i];
        offs[i] = run;
        run += v;
    }
    totals[b] = run;
}

// fused exclusive scan over nbucket elements; single block of 1024
__global__ __launch_bounds__(1024) void scan_fused_k(
    const int* __restrict__ totals, int* __restrict__ bucket_start, int nbucket)
{
    __shared__ int sm[1024];
    __shared__ int carry_s;
    if (threadIdx.x == 0) carry_s = 0;
    __syncthreads();
    int ntile = (nbucket + 1023) / 1024;
    for (int t = 0; t < ntile; ++t) {
        int i = t * 1024 + threadIdx.x;
        int v = (i < nbucket) ? totals[i] : 0;
        sm[threadIdx.x] = v;
        __syncthreads();
        for (int off = 1; off < 1024; off <<= 1) {
            int add = (threadIdx.x >= off) ? sm[threadIdx.x - off] : 0;
            __syncthreads();
            sm[threadIdx.x] += add;
            __syncthreads();
        }
        int c0 = carry_s;
        if (i < nbucket) bucket_start[i] = c0 + sm[threadIdx.x] - v;
        __syncthreads();
        if (threadIdx.x == 1023) carry_s = c0 + sm[1023];
        __syncthreads();
    }
    if (threadIdx.x == 0) bucket_start[nbucket] = carry_s;   // == E
}

// pass C: partition edges into bucket segments; LDS cursors only.
// cursor init = local chunk offset + global bucket base.
// edge payload: .x = (row&15)<<17 | col  (col < 2^17), .y = val bits
__global__ __launch_bounds__(256) void scatter3_k(
    const int* __restrict__ rows, const int* __restrict__ cols,
    const float* __restrict__ vals, const int* __restrict__ offs,
    const int* __restrict__ bucket_start,
    int2* __restrict__ edges, int E, int chunkE)
{
    __shared__ int cur[NBUCKET];
    int c = blockIdx.x;
    const int* o = offs + (long)c * NBUCKET;
    for (int b = threadIdx.x; b < NBUCKET; b += 256)
        cur[b] = o[b] + bucket_start[b];
    __syncthreads();
    int s = c * chunkE;
    int e = min(s + chunkE, E);
    for (int j = s + (int)threadIdx.x; j < e; j += 256) {
        int r = rows[j];
        int pos = atomicAdd(&cur[r >> BSHIFT], 1);
        edges[pos] = make_int2(((r & BMASK) << 17) | cols[j],
                               __float_as_int(vals[j]));
    }
}

// pass D: per-bucket LDS counting sort over the 16 row-locals.
// One wave per bucket; intra-wave program order -> no barriers needed.
// Produces exact row-sorted edges2 and row_start[N+1].
__global__ __launch_bounds__(256) void sort_bkt_k(
    const int* __restrict__ bucket_start, const int2* __restrict__ edges_in,
    int2* __restrict__ edges_out, int* __restrict__ row_start, int nbucket)
{
    __shared__ int cur[4][16];
    int w = (int)(threadIdx.x >> 6);
    int lane = (int)(threadIdx.x & 63);
    int bk = blockIdx.x * 4 + w;
    if (bk >= nbucket) return;
    int s = bucket_start[bk];
    int e = bucket_start[bk + 1];
    if (lane < 16) cur[w][lane] = 0;
    for (int j = s + lane; j < e; j += 64)
        atomicAdd(&cur[w][(unsigned)edges_in[j].x >> 17], 1);
    if (lane == 0) {
        int run = s;
        #pragma unroll
        for (int r = 0; r < 16; ++r) {
            int c = cur[w][r];
            cur[w][r] = run;
            row_start[bk * 16 + r] = run;
            run += c;
        }
    }
    for (int j = s + lane; j < e; j += 64) {
        int2 ed = edges_in[j];
        int pos = atomicAdd(&cur[w][(unsigned)ed.x >> 17], 1);
        edges_out[pos] = ed;
    }
    if (bk == nbucket - 1 && lane == 0) row_start[nbucket * 16] = e;  // == E
}

// spmm: one wave per row; lane = feature dim; scalar edge stream;
// 8 independent gather chains; bf16 in/out, fp32 accumulate.
__global__ __launch_bounds__(256) void spmm_csr_k(
    const int* __restrict__ row_start, const int2* __restrict__ edges,
    const ushort* __restrict__ x, ushort* __restrict__ y, int N)
{
    int wid = __builtin_amdgcn_readfirstlane((int)(threadIdx.x >> 6));
    int r = blockIdx.x * 4 + wid;
    if (r >= N) return;
    int d = (int)(threadIdx.x & 63);
    int s = row_start[r];      // wave-uniform -> s_load
    int e = row_start[r + 1];
    float a0 = 0.f, a1 = 0.f, a2 = 0.f, a3 = 0.f;
    float a4 = 0.f, a5 = 0.f, a6 = 0.f, a7 = 0.f;
    int j = s;
    for (; j + 8 <= e; j += 8) {
        int2 e0 = edges[j];
        int2 e1 = edges[j + 1];
        int2 e2 = edges[j + 2];
        int2 e3 = edges[j + 3];
        int2 e4 = edges[j + 4];
        int2 e5 = edges[j + 5];
        int2 e6 = edges[j + 6];
        int2 e7 = edges[j + 7];
        a0 += __int_as_float(e0.y) * bf2f(x[(long)(e0.x & 0x1FFFF) * 64 + d]);
        a1 += __int_as_float(e1.y) * bf2f(x[(long)(e1.x & 0x1FFFF) * 64 + d]);
        a2 += __int_as_float(e2.y) * bf2f(x[(long)(e2.x & 0x1FFFF) * 64 + d]);
        a3 += __int_as_float(e3.y) * bf2f(x[(long)(e3.x & 0x1FFFF) * 64 + d]);
        a4 += __int_as_float(e4.y) * bf2f(x[(long)(e4.x & 0x1FFFF) * 64 + d]);
        a5 += __int_as_float(e5.y) * bf2f(x[(long)(e5.x & 0x1FFFF) * 64 + d]);
        a6 += __int_as_float(e6.y) * bf2f(x[(long)(e6.x & 0x1FFFF) * 64 + d]);
        a7 += __int_as_float(e7.y) * bf2f(x[(long)(e7.x & 0x1FFFF) * 64 + d]);
    }
    for (; j + 4 <= e; j += 4) {
        int2 e0 = edges[j];
        int2 e1 = edges[j + 1];
        int2 e2 = edges[j + 2];
        int2 e3 = edges[j + 3];
        a0 += __int_as_float(e0.y) * bf2f(x[(long)(e0.x & 0x1FFFF) * 64 + d]);
        a1 += __int_as_float(e1.y) * bf2f(x[(long)(e1.x & 0x1FFFF) * 64 + d]);
        a2 += __int_as_float(e2.y) * bf2f(x[(long)(e2.x & 0x1FFFF) * 64 + d]);
        a3 += __int_as_float(e3.y) * bf2f(x[(long)(e3.x & 0x1FFFF) * 64 + d]);
    }
    for (; j < e; ++j) {
        int2 e0 = edges[j];
        a0 += __int_as_float(e0.y) * bf2f(x[(long)(e0.x & 0x1FFFF) * 64 + d]);
    }
    float sum = ((a0 + a1) + (a2 + a3)) + ((a4 + a5) + (a6 + a7));
    y[(long)r * 64 + d] = f2bf(sum);
}

// out[0..2] = 0.25*emb[idx] (hop-0 term), out[3..5] = emb[idx]; float4 lanes
__global__ __launch_bounds__(256) void init_out_k(
    const float* __restrict__ emb, const int* __restrict__ n0,
    const int* __restrict__ n1, const int* __restrict__ n2,
    float* __restrict__ out, int B)
{
    int tid = blockIdx.x * blockDim.x + threadIdx.x;
    int total = 3 * B * 16;                 // float4 granularity
    if (tid >= total) return;
    int arr = tid / (B * 16);
    int rem = tid - arr * (B * 16);
    int b = rem >> 4;
    int d4 = rem & 15;
    const int* __restrict__ idx = (arr == 0) ? n0 : ((arr == 1) ? n1 : n2);
    float4 v = *(const float4*)(emb + (long)idx[b] * 64 + d4 * 4);
    float4 q = make_float4(0.25f * v.x, 0.25f * v.y, 0.25f * v.z, 0.25f * v.w);
    *(float4*)(out + (long)arr * B * 64 + (long)rem * 4) = q;
    *(float4*)(out + (long)(arr + 3) * B * 64 + (long)rem * 4) = v;
}

// pooled += 0.25 * agg_bf16[idx]
__global__ __launch_bounds__(256) void gather_add_k(
    const ushort* __restrict__ agg, const int* __restrict__ n0,
    const int* __restrict__ n1, const int* __restrict__ n2,
    float* __restrict__ out, int B)
{
    int tid = blockIdx.x * blockDim.x + threadIdx.x;
    int total = 3 * B * 16;
    if (tid >= total) return;
    int arr = tid / (B * 16);
    int rem = tid - arr * (B * 16);
    int b = rem >> 4;
    int d4 = rem & 15;
    const int* __restrict__ idx = (arr == 0) ? n0 : ((arr == 1) ? n1 : n2);
    ushort4 v = *(const ushort4*)(agg + (long)idx[b] * 64 + d4 * 4);
    float* o = out + (long)arr * B * 64 + (long)rem * 4;
    float4 cur = *(float4*)o;
    cur.x += 0.25f * bf2f(v.x); cur.y += 0.25f * bf2f(v.y);
    cur.z += 0.25f * bf2f(v.z); cur.w += 0.25f * bf2f(v.w);
    *(float4*)o = cur;
}

extern "C" void kernel_launch(void* const* d_in, const int* in_sizes, int n_in,
                              void* d_out, int out_size, void* d_ws, size_t ws_size,
                              hipStream_t stream)
{
    const float* emb  = (const float*)d_in[0];
    const int*   rows = (const int*)d_in[1];
    const int*   cols = (const int*)d_in[2];
    const float* vals = (const float*)d_in[3];
    const int*   node = (const int*)d_in[4];
    const int*   pos  = (const int*)d_in[5];
    const int*   neg  = (const int*)d_in[6];
    float* out = (float*)d_out;

    const int E = in_sizes[1];
    const int B = in_sizes[4];
    const int N = in_sizes[0] / 64;
    const size_t nd = (size_t)N * 64;
    const int chunkE = (E + NCHUNK - 1) / NCHUNK;
    const int nbucket = (N + BMASK) >> BSHIFT;     // 6250 for N=100000

    // workspace layout
    ushort* aggA        = (ushort*)d_ws;            // N*64 bf16
    ushort* aggB        = aggA + nd;                // N*64 bf16 (also emb cast)
    int2*  edges        = (int2*)(aggB + nd);       // E (bucket-grouped)
    int2*  edges2       = edges + E;                // E (row-sorted)
    int*   cnt          = (int*)(edges2 + E);       // NCHUNK * NBUCKET
    int*   totals       = cnt + (long)NCHUNK * NBUCKET;  // NBUCKET
    int*   bucket_start = totals + NBUCKET;         // NBUCKET+1
    int*   row_start    = bucket_start + NBUCKET + 1;    // N+1
    // offs reuses edges2's storage: written by localscan, read by scatter3,
    // dead before sort_bkt writes edges2 (stream-ordered).
    int*   offs         = (int*)edges2;             // NCHUNK * NBUCKET

    const int gtotal   = 3 * B * 16;
    const int gblocks  = (gtotal + 255) / 256;
    const int cblocks  = ((int)(nd / 4) + 255) / 256;
    const int bblocks  = (nbucket + 255) / 256;     // 25
    const int dblocks  = (nbucket + 3) / 4;         // sortD: 4 buckets/block
    const int rblocks  = (N + 3) / 4;               // spmm: 4 rows/block

    init_out_k<<<gblocks, 256, 0, stream>>>(emb, node, pos, neg, out, B);
    f2bf_k<<<cblocks, 256, 0, stream>>>(emb, aggB, (int)(nd / 4));

    // ---- bucketed partition + per-bucket counting sort; no global atomics ----
    count_k<<<NCHUNK, 256, 0, stream>>>(rows, cnt, E, chunkE);
    localscan_k<<<bblocks, 256, 0, stream>>>(cnt, offs, totals);
    scan_fused_k<<<1, 1024, 0, stream>>>(totals, bucket_start, nbucket);
    scatter3_k<<<NCHUNK, 256, 0, stream>>>(rows, cols, vals, offs, bucket_start, edges, E, chunkE);
    sort_bkt_k<<<dblocks, 256, 0, stream>>>(bucket_start, edges, edges2, row_start, nbucket);

    // ---- 3 propagation hops, row-wave register-accumulating spmm ----
    spmm_csr_k<<<rblocks, 256, 0, stream>>>(row_start, edges2, aggB, aggA, N);
    gather_add_k<<<gblocks, 256, 0, stream>>>(aggA, node, pos, neg, out, B);

    spmm_csr_k<<<rblocks, 256, 0, stream>>>(row_start, edges2, aggA, aggB, N);
    gather_add_k<<<gblocks, 256, 0, stream>>>(aggB, node, pos, neg, out, B);

    spmm_csr_k<<<rblocks, 256, 0, stream>>>(row_start, edges2, aggB, aggA, N);
    gather_add_k<<<gblocks, 256, 0, stream>>>(aggA, node, pos, neg, out, B);
}

// Round 10
// 219.515 us; speedup vs baseline: 8.7141x; 1.0274x over previous
//
#include <hip/hip_runtime.h>

// LightGCN 3-hop propagation, D=64, bf16 features / fp32 accumulate.
// R10: R9 counters — scatter3_k 52us at Occupancy 6.8%, VALUBusy 1.2%:
// NCHUNK=256 blocks = 1 block/CU x 4 waves -> no latency hiding for its
// ~24-iteration load/LDS-atomic/scattered-store loop. Fix: 1024-thread
// blocks for count_k and scatter3_k (16 waves/CU, 4x MLP; same work, same
// LDS). Everything else unchanged from R9.

#define NBUCKET 6250     // N=100000 rows, 16 per bucket
#define BSHIFT  4
#define BMASK   15
#define NCHUNK  256      // edge chunks; E=1.6M -> 6250 edges/chunk

static __device__ __forceinline__ ushort f2bf(float f) {
    unsigned u = __float_as_uint(f);
    unsigned r = (u + 0x7fffu + ((u >> 16) & 1u)) >> 16;   // RNE
    return (ushort)r;
}
static __device__ __forceinline__ float bf2f(ushort b) {
    return __uint_as_float(((unsigned)b) << 16);
}

__global__ __launch_bounds__(256) void f2bf_k(
    const float* __restrict__ in, ushort* __restrict__ out, int n4)
{
    int i = blockIdx.x * blockDim.x + threadIdx.x;
    if (i >= n4) return;
    float4 v = *(const float4*)(in + (long)i * 4);
    ushort4 o;
    o.x = f2bf(v.x); o.y = f2bf(v.y); o.z = f2bf(v.z); o.w = f2bf(v.w);
    *(ushort4*)(out + (long)i * 4) = o;
}

// pass A: per-chunk bucket histogram in LDS (no global atomics); 16 waves
__global__ __launch_bounds__(1024) void count_k(
    const int* __restrict__ rows, int* __restrict__ cnt, int E, int chunkE)
{
    __shared__ unsigned h[NBUCKET];
    int c = blockIdx.x;
    for (int b = threadIdx.x; b < NBUCKET; b += 1024) h[b] = 0u;
    __syncthreads();
    int s = c * chunkE;
    int e = min(s + chunkE, E);
    for (int j = s + (int)threadIdx.x; j < e; j += 1024)
        atomicAdd(&h[rows[j] >> BSHIFT], 1u);
    __syncthreads();
    int* o = cnt + (long)c * NBUCKET;
    for (int b = threadIdx.x; b < NBUCKET; b += 1024) o[b] = (int)h[b];
}

// pass B: per-bucket local exclusive prefix over chunks + bucket totals.
__global__ __launch_bounds__(256) void localscan_k(
    const int* __restrict__ cnt, int* __restrict__ offs,
    int* __restrict__ totals)
{
    int b = blockIdx.x * 256 + threadIdx.x;
    if (b >= NBUCKET) return;
    int run = 0;
    #pragma unroll 8
    for (int c = 0; c < NCHUNK; ++c) {
        long i = (long)c * NBUCKET + b;
        int v = cnt[i];
        offs[i] = run;
        run += v;
    }
    totals[b] = run;
}

// fused exclusive scan over nbucket elements; single block of 1024
__global__ __launch_bounds__(1024) void scan_fused_k(
    const int* __restrict__ totals, int* __restrict__ bucket_start, int nbucket)
{
    __shared__ int sm[1024];
    __shared__ int carry_s;
    if (threadIdx.x == 0) carry_s = 0;
    __syncthreads();
    int ntile = (nbucket + 1023) / 1024;
    for (int t = 0; t < ntile; ++t) {
        int i = t * 1024 + threadIdx.x;
        int v = (i < nbucket) ? totals[i] : 0;
        sm[threadIdx.x] = v;
        __syncthreads();
        for (int off = 1; off < 1024; off <<= 1) {
            int add = (threadIdx.x >= off) ? sm[threadIdx.x - off] : 0;
            __syncthreads();
            sm[threadIdx.x] += add;
            __syncthreads();
        }
        int c0 = carry_s;
        if (i < nbucket) bucket_start[i] = c0 + sm[threadIdx.x] - v;
        __syncthreads();
        if (threadIdx.x == 1023) carry_s = c0 + sm[1023];
        __syncthreads();
    }
    if (threadIdx.x == 0) bucket_start[nbucket] = carry_s;   // == E
}

// pass C: partition edges into bucket segments; LDS cursors only; 16 waves.
// cursor init = local chunk offset + global bucket base.
// edge payload: .x = (row&15)<<17 | col  (col < 2^17), .y = val bits
__global__ __launch_bounds__(1024) void scatter3_k(
    const int* __restrict__ rows, const int* __restrict__ cols,
    const float* __restrict__ vals, const int* __restrict__ offs,
    const int* __restrict__ bucket_start,
    int2* __restrict__ edges, int E, int chunkE)
{
    __shared__ int cur[NBUCKET];
    int c = blockIdx.x;
    const int* o = offs + (long)c * NBUCKET;
    for (int b = threadIdx.x; b < NBUCKET; b += 1024)
        cur[b] = o[b] + bucket_start[b];
    __syncthreads();
    int s = c * chunkE;
    int e = min(s + chunkE, E);
    for (int j = s + (int)threadIdx.x; j < e; j += 1024) {
        int r = rows[j];
        int pos = atomicAdd(&cur[r >> BSHIFT], 1);
        edges[pos] = make_int2(((r & BMASK) << 17) | cols[j],
                               __float_as_int(vals[j]));
    }
}

// pass D: per-bucket LDS counting sort over the 16 row-locals.
// One wave per bucket; intra-wave program order -> no barriers needed.
__global__ __launch_bounds__(256) void sort_bkt_k(
    const int* __restrict__ bucket_start, const int2* __restrict__ edges_in,
    int2* __restrict__ edges_out, int* __restrict__ row_start, int nbucket)
{
    __shared__ int cur[4][16];
    int w = (int)(threadIdx.x >> 6);
    int lane = (int)(threadIdx.x & 63);
    int bk = blockIdx.x * 4 + w;
    if (bk >= nbucket) return;
    int s = bucket_start[bk];
    int e = bucket_start[bk + 1];
    if (lane < 16) cur[w][lane] = 0;
    for (int j = s + lane; j < e; j += 64)
        atomicAdd(&cur[w][(unsigned)edges_in[j].x >> 17], 1);
    if (lane == 0) {
        int run = s;
        #pragma unroll
        for (int r = 0; r < 16; ++r) {
            int c = cur[w][r];
            cur[w][r] = run;
            row_start[bk * 16 + r] = run;
            run += c;
        }
    }
    for (int j = s + lane; j < e; j += 64) {
        int2 ed = edges_in[j];
        int pos = atomicAdd(&cur[w][(unsigned)ed.x >> 17], 1);
        edges_out[pos] = ed;
    }
    if (bk == nbucket - 1 && lane == 0) row_start[nbucket * 16] = e;  // == E
}

// spmm: one wave per row; lane = feature dim; scalar edge stream;
// 8 independent gather chains; bf16 in/out, fp32 accumulate.
__global__ __launch_bounds__(256) void spmm_csr_k(
    const int* __restrict__ row_start, const int2* __restrict__ edges,
    const ushort* __restrict__ x, ushort* __restrict__ y, int N)
{
    int wid = __builtin_amdgcn_readfirstlane((int)(threadIdx.x >> 6));
    int r = blockIdx.x * 4 + wid;
    if (r >= N) return;
    int d = (int)(threadIdx.x & 63);
    int s = row_start[r];      // wave-uniform -> s_load
    int e = row_start[r + 1];
    float a0 = 0.f, a1 = 0.f, a2 = 0.f, a3 = 0.f;
    float a4 = 0.f, a5 = 0.f, a6 = 0.f, a7 = 0.f;
    int j = s;
    for (; j + 8 <= e; j += 8) {
        int2 e0 = edges[j];
        int2 e1 = edges[j + 1];
        int2 e2 = edges[j + 2];
        int2 e3 = edges[j + 3];
        int2 e4 = edges[j + 4];
        int2 e5 = edges[j + 5];
        int2 e6 = edges[j + 6];
        int2 e7 = edges[j + 7];
        a0 += __int_as_float(e0.y) * bf2f(x[(long)(e0.x & 0x1FFFF) * 64 + d]);
        a1 += __int_as_float(e1.y) * bf2f(x[(long)(e1.x & 0x1FFFF) * 64 + d]);
        a2 += __int_as_float(e2.y) * bf2f(x[(long)(e2.x & 0x1FFFF) * 64 + d]);
        a3 += __int_as_float(e3.y) * bf2f(x[(long)(e3.x & 0x1FFFF) * 64 + d]);
        a4 += __int_as_float(e4.y) * bf2f(x[(long)(e4.x & 0x1FFFF) * 64 + d]);
        a5 += __int_as_float(e5.y) * bf2f(x[(long)(e5.x & 0x1FFFF) * 64 + d]);
        a6 += __int_as_float(e6.y) * bf2f(x[(long)(e6.x & 0x1FFFF) * 64 + d]);
        a7 += __int_as_float(e7.y) * bf2f(x[(long)(e7.x & 0x1FFFF) * 64 + d]);
    }
    for (; j + 4 <= e; j += 4) {
        int2 e0 = edges[j];
        int2 e1 = edges[j + 1];
        int2 e2 = edges[j + 2];
        int2 e3 = edges[j + 3];
        a0 += __int_as_float(e0.y) * bf2f(x[(long)(e0.x & 0x1FFFF) * 64 + d]);
        a1 += __int_as_float(e1.y) * bf2f(x[(long)(e1.x & 0x1FFFF) * 64 + d]);
        a2 += __int_as_float(e2.y) * bf2f(x[(long)(e2.x & 0x1FFFF) * 64 + d]);
        a3 += __int_as_float(e3.y) * bf2f(x[(long)(e3.x & 0x1FFFF) * 64 + d]);
    }
    for (; j < e; ++j) {
        int2 e0 = edges[j];
        a0 += __int_as_float(e0.y) * bf2f(x[(long)(e0.x & 0x1FFFF) * 64 + d]);
    }
    float sum = ((a0 + a1) + (a2 + a3)) + ((a4 + a5) + (a6 + a7));
    y[(long)r * 64 + d] = f2bf(sum);
}

// out[0..2] = 0.25*emb[idx] (hop-0 term), out[3..5] = emb[idx]; float4 lanes
__global__ __launch_bounds__(256) void init_out_k(
    const float* __restrict__ emb, const int* __restrict__ n0,
    const int* __restrict__ n1, const int* __restrict__ n2,
    float* __restrict__ out, int B)
{
    int tid = blockIdx.x * blockDim.x + threadIdx.x;
    int total = 3 * B * 16;                 // float4 granularity
    if (tid >= total) return;
    int arr = tid / (B * 16);
    int rem = tid - arr * (B * 16);
    int b = rem >> 4;
    int d4 = rem & 15;
    const int* __restrict__ idx = (arr == 0) ? n0 : ((arr == 1) ? n1 : n2);
    float4 v = *(const float4*)(emb + (long)idx[b] * 64 + d4 * 4);
    float4 q = make_float4(0.25f * v.x, 0.25f * v.y, 0.25f * v.z, 0.25f * v.w);
    *(float4*)(out + (long)arr * B * 64 + (long)rem * 4) = q;
    *(float4*)(out + (long)(arr + 3) * B * 64 + (long)rem * 4) = v;
}

// pooled += 0.25 * agg_bf16[idx]
__global__ __launch_bounds__(256) void gather_add_k(
    const ushort* __restrict__ agg, const int* __restrict__ n0,
    const int* __restrict__ n1, const int* __restrict__ n2,
    float* __restrict__ out, int B)
{
    int tid = blockIdx.x * blockDim.x + threadIdx.x;
    int total = 3 * B * 16;
    if (tid >= total) return;
    int arr = tid / (B * 16);
    int rem = tid - arr * (B * 16);
    int b = rem >> 4;
    int d4 = rem & 15;
    const int* __restrict__ idx = (arr == 0) ? n0 : ((arr == 1) ? n1 : n2);
    ushort4 v = *(const ushort4*)(agg + (long)idx[b] * 64 + d4 * 4);
    float* o = out + (long)arr * B * 64 + (long)rem * 4;
    float4 cur = *(float4*)o;
    cur.x += 0.25f * bf2f(v.x); cur.y += 0.25f * bf2f(v.y);
    cur.z += 0.25f * bf2f(v.z); cur.w += 0.25f * bf2f(v.w);
    *(float4*)o = cur;
}

extern "C" void kernel_launch(void* const* d_in, const int* in_sizes, int n_in,
                              void* d_out, int out_size, void* d_ws, size_t ws_size,
                              hipStream_t stream)
{
    const float* emb  = (const float*)d_in[0];
    const int*   rows = (const int*)d_in[1];
    const int*   cols = (const int*)d_in[2];
    const float* vals = (const float*)d_in[3];
    const int*   node = (const int*)d_in[4];
    const int*   pos  = (const int*)d_in[5];
    const int*   neg  = (const int*)d_in[6];
    float* out = (float*)d_out;

    const int E = in_sizes[1];
    const int B = in_sizes[4];
    const int N = in_sizes[0] / 64;
    const size_t nd = (size_t)N * 64;
    const int chunkE = (E + NCHUNK - 1) / NCHUNK;
    const int nbucket = (N + BMASK) >> BSHIFT;     // 6250 for N=100000

    // workspace layout
    ushort* aggA        = (ushort*)d_ws;            // N*64 bf16
    ushort* aggB        = aggA + nd;                // N*64 bf16 (also emb cast)
    int2*  edges        = (int2*)(aggB + nd);       // E (bucket-grouped)
    int2*  edges2       = edges + E;                // E (row-sorted)
    int*   cnt          = (int*)(edges2 + E);       // NCHUNK * NBUCKET
    int*   totals       = cnt + (long)NCHUNK * NBUCKET;  // NBUCKET
    int*   bucket_start = totals + NBUCKET;         // NBUCKET+1
    int*   row_start    = bucket_start + NBUCKET + 1;    // N+1
    // offs reuses edges2's storage: written by localscan, read by scatter3,
    // dead before sort_bkt writes edges2 (stream-ordered).
    int*   offs         = (int*)edges2;             // NCHUNK * NBUCKET

    const int gtotal   = 3 * B * 16;
    const int gblocks  = (gtotal + 255) / 256;
    const int cblocks  = ((int)(nd / 4) + 255) / 256;
    const int bblocks  = (nbucket + 255) / 256;     // 25
    const int dblocks  = (nbucket + 3) / 4;         // sortD: 4 buckets/block
    const int rblocks  = (N + 3) / 4;               // spmm: 4 rows/block

    init_out_k<<<gblocks, 256, 0, stream>>>(emb, node, pos, neg, out, B);
    f2bf_k<<<cblocks, 256, 0, stream>>>(emb, aggB, (int)(nd / 4));

    // ---- bucketed partition + per-bucket counting sort; no global atomics ----
    count_k<<<NCHUNK, 1024, 0, stream>>>(rows, cnt, E, chunkE);
    localscan_k<<<bblocks, 256, 0, stream>>>(cnt, offs, totals);
    scan_fused_k<<<1, 1024, 0, stream>>>(totals, bucket_start, nbucket);
    scatter3_k<<<NCHUNK, 1024, 0, stream>>>(rows, cols, vals, offs, bucket_start, edges, E, chunkE);
    sort_bkt_k<<<dblocks, 256, 0, stream>>>(bucket_start, edges, edges2, row_start, nbucket);

    // ---- 3 propagation hops, row-wave register-accumulating spmm ----
    spmm_csr_k<<<rblocks, 256, 0, stream>>>(row_start, edges2, aggB, aggA, N);
    gather_add_k<<<gblocks, 256, 0, stream>>>(aggA, node, pos, neg, out, B);

    spmm_csr_k<<<rblocks, 256, 0, stream>>>(row_start, edges2, aggA, aggB, N);
    gather_add_k<<<gblocks, 256, 0, stream>>>(aggB, node, pos, neg, out, B);

    spmm_csr_k<<<rblocks, 256, 0, stream>>>(row_start, edges2, aggB, aggA, N);
    gather_add_k<<<gblocks, 256, 0, stream>>>(aggA, node, pos, neg, out, B);
}

// Round 11
// 219.357 us; speedup vs baseline: 8.7204x; 1.0007x over previous
//
#include <hip/hip_runtime.h>

// LightGCN 3-hop propagation, D=64, bf16 features / fp32 accumulate.
// R10: R9 counters — scatter3_k 52us at Occupancy 6.8%, VALUBusy 1.2%:
// NCHUNK=256 blocks = 1 block/CU x 4 waves -> no latency hiding for its
// ~24-iteration load/LDS-atomic/scattered-store loop. Fix: 1024-thread
// blocks for count_k and scatter3_k (16 waves/CU, 4x MLP; same work, same
// LDS). Everything else unchanged from R9.

#define NBUCKET 6250     // N=100000 rows, 16 per bucket
#define BSHIFT  4
#define BMASK   15
#define NCHUNK  256      // edge chunks; E=1.6M -> 6250 edges/chunk

static __device__ __forceinline__ ushort f2bf(float f) {
    unsigned u = __float_as_uint(f);
    unsigned r = (u + 0x7fffu + ((u >> 16) & 1u)) >> 16;   // RNE
    return (ushort)r;
}
static __device__ __forceinline__ float bf2f(ushort b) {
    return __uint_as_float(((unsigned)b) << 16);
}

__global__ __launch_bounds__(256) void f2bf_k(
    const float* __restrict__ in, ushort* __restrict__ out, int n4)
{
    int i = blockIdx.x * blockDim.x + threadIdx.x;
    if (i >= n4) return;
    float4 v = *(const float4*)(in + (long)i * 4);
    ushort4 o;
    o.x = f2bf(v.x); o.y = f2bf(v.y); o.z = f2bf(v.z); o.w = f2bf(v.w);
    *(ushort4*)(out + (long)i * 4) = o;
}

// pass A: per-chunk bucket histogram in LDS (no global atomics); 16 waves
__global__ __launch_bounds__(1024) void count_k(
    const int* __restrict__ rows, int* __restrict__ cnt, int E, int chunkE)
{
    __shared__ unsigned h[NBUCKET];
    int c = blockIdx.x;
    for (int b = threadIdx.x; b < NBUCKET; b += 1024) h[b] = 0u;
    __syncthreads();
    int s = c * chunkE;
    int e = min(s + chunkE, E);
    for (int j = s + (int)threadIdx.x; j < e; j += 1024)
        atomicAdd(&h[rows[j] >> BSHIFT], 1u);
    __syncthreads();
    int* o = cnt + (long)c * NBUCKET;
    for (int b = threadIdx.x; b < NBUCKET; b += 1024) o[b] = (int)h[b];
}

// pass B: per-bucket local exclusive prefix over chunks + bucket totals.
__global__ __launch_bounds__(256) void localscan_k(
    const int* __restrict__ cnt, int* __restrict__ offs,
    int* __restrict__ totals)
{
    int b = blockIdx.x * 256 + threadIdx.x;
    if (b >= NBUCKET) return;
    int run = 0;
    #pragma unroll 8
    for (int c = 0; c < NCHUNK; ++c) {
        long i = (long)c * NBUCKET + b;
        int v = cnt[i];
        offs[i] = run;
        run += v;
    }
    totals[b] = run;
}

// fused exclusive scan over nbucket elements; single block of 1024
__global__ __launch_bounds__(1024) void scan_fused_k(
    const int* __restrict__ totals, int* __restrict__ bucket_start, int nbucket)
{
    __shared__ int sm[1024];
    __shared__ int carry_s;
    if (threadIdx.x == 0) carry_s = 0;
    __syncthreads();
    int ntile = (nbucket + 1023) / 1024;
    for (int t = 0; t < ntile; ++t) {
        int i = t * 1024 + threadIdx.x;
        int v = (i < nbucket) ? totals[i] : 0;
        sm[threadIdx.x] = v;
        __syncthreads();
        for (int off = 1; off < 1024; off <<= 1) {
            int add = (threadIdx.x >= off) ? sm[threadIdx.x - off] : 0;
            __syncthreads();
            sm[threadIdx.x] += add;
            __syncthreads();
        }
        int c0 = carry_s;
        if (i < nbucket) bucket_start[i] = c0 + sm[threadIdx.x] - v;
        __syncthreads();
        if (threadIdx.x == 1023) carry_s = c0 + sm[1023];
        __syncthreads();
    }
    if (threadIdx.x == 0) bucket_start[nbucket] = carry_s;   // == E
}

// pass C: partition edges into bucket segments; LDS cursors only; 16 waves.
// cursor init = local chunk offset + global bucket base.
// edge payload: .x = (row&15)<<17 | col  (col < 2^17), .y = val bits
__global__ __launch_bounds__(1024) void scatter3_k(
    const int* __restrict__ rows, const int* __restrict__ cols,
    const float* __restrict__ vals, const int* __restrict__ offs,
    const int* __restrict__ bucket_start,
    int2* __restrict__ edges, int E, int chunkE)
{
    __shared__ int cur[NBUCKET];
    int c = blockIdx.x;
    const int* o = offs + (long)c * NBUCKET;
    for (int b = threadIdx.x; b < NBUCKET; b += 1024)
        cur[b] = o[b] + bucket_start[b];
    __syncthreads();
    int s = c * chunkE;
    int e = min(s + chunkE, E);
    for (int j = s + (int)threadIdx.x; j < e; j += 1024) {
        int r = rows[j];
        int pos = atomicAdd(&cur[r >> BSHIFT], 1);
        edges[pos] = make_int2(((r & BMASK) << 17) | cols[j],
                               __float_as_int(vals[j]));
    }
}

// pass D: per-bucket LDS counting sort over the 16 row-locals.
// One wave per bucket; intra-wave program order -> no barriers needed.
__global__ __launch_bounds__(256) void sort_bkt_k(
    const int* __restrict__ bucket_start, const int2* __restrict__ edges_in,
    int2* __restrict__ edges_out, int* __restrict__ row_start, int nbucket)
{
    __shared__ int cur[4][16];
    int w = (int)(threadIdx.x >> 6);
    int lane = (int)(threadIdx.x & 63);
    int bk = blockIdx.x * 4 + w;
    if (bk >= nbucket) return;
    int s = bucket_start[bk];
    int e = bucket_start[bk + 1];
    if (lane < 16) cur[w][lane] = 0;
    for (int j = s + lane; j < e; j += 64)
        atomicAdd(&cur[w][(unsigned)edges_in[j].x >> 17], 1);
    if (lane == 0) {
        int run = s;
        #pragma unroll
        for (int r = 0; r < 16; ++r) {
            int c = cur[w][r];
            cur[w][r] = run;
            row_start[bk * 16 + r] = run;
            run += c;
        }
    }
    for (int j = s + lane; j < e; j += 64) {
        int2 ed = edges_in[j];
        int pos = atomicAdd(&cur[w][(unsigned)ed.x >> 17], 1);
        edges_out[pos] = ed;
    }
    if (bk == nbucket - 1 && lane == 0) row_start[nbucket * 16] = e;  // == E
}

// spmm: one wave per row; lane = feature dim; scalar edge stream;
// 8 independent gather chains; bf16 in/out, fp32 accumulate.
__global__ __launch_bounds__(256) void spmm_csr_k(
    const int* __restrict__ row_start, const int2* __restrict__ edges,
    const ushort* __restrict__ x, ushort* __restrict__ y, int N)
{
    int wid = __builtin_amdgcn_readfirstlane((int)(threadIdx.x >> 6));
    int r = blockIdx.x * 4 + wid;
    if (r >= N) return;
    int d = (int)(threadIdx.x & 63);
    int s = row_start[r];      // wave-uniform -> s_load
    int e = row_start[r + 1];
    float a0 = 0.f, a1 = 0.f, a2 = 0.f, a3 = 0.f;
    float a4 = 0.f, a5 = 0.f, a6 = 0.f, a7 = 0.f;
    int j = s;
    for (; j + 8 <= e; j += 8) {
        int2 e0 = edges[j];
        int2 e1 = edges[j + 1];
        int2 e2 = edges[j + 2];
        int2 e3 = edges[j + 3];
        int2 e4 = edges[j + 4];
        int2 e5 = edges[j + 5];
        int2 e6 = edges[j + 6];
        int2 e7 = edges[j + 7];
        a0 += __int_as_float(e0.y) * bf2f(x[(long)(e0.x & 0x1FFFF) * 64 + d]);
        a1 += __int_as_float(e1.y) * bf2f(x[(long)(e1.x & 0x1FFFF) * 64 + d]);
        a2 += __int_as_float(e2.y) * bf2f(x[(long)(e2.x & 0x1FFFF) * 64 + d]);
        a3 += __int_as_float(e3.y) * bf2f(x[(long)(e3.x & 0x1FFFF) * 64 + d]);
        a4 += __int_as_float(e4.y) * bf2f(x[(long)(e4.x & 0x1FFFF) * 64 + d]);
        a5 += __int_as_float(e5.y) * bf2f(x[(long)(e5.x & 0x1FFFF) * 64 + d]);
        a6 += __int_as_float(e6.y) * bf2f(x[(long)(e6.x & 0x1FFFF) * 64 + d]);
        a7 += __int_as_float(e7.y) * bf2f(x[(long)(e7.x & 0x1FFFF) * 64 + d]);
    }
    for (; j + 4 <= e; j += 4) {
        int2 e0 = edges[j];
        int2 e1 = edges[j + 1];
        int2 e2 = edges[j + 2];
        int2 e3 = edges[j + 3];
        a0 += __int_as_float(e0.y) * bf2f(x[(long)(e0.x & 0x1FFFF) * 64 + d]);
        a1 += __int_as_float(e1.y) * bf2f(x[(long)(e1.x & 0x1FFFF) * 64 + d]);
        a2 += __int_as_float(e2.y) * bf2f(x[(long)(e2.x & 0x1FFFF) * 64 + d]);
        a3 += __int_as_float(e3.y) * bf2f(x[(long)(e3.x & 0x1FFFF) * 64 + d]);
    }
    for (; j < e; ++j) {
        int2 e0 = edges[j];
        a0 += __int_as_float(e0.y) * bf2f(x[(long)(e0.x & 0x1FFFF) * 64 + d]);
    }
    float sum = ((a0 + a1) + (a2 + a3)) + ((a4 + a5) + (a6 + a7));
    y[(long)r * 64 + d] = f2bf(sum);
}

// out[0..2] = 0.25*emb[idx] (hop-0 term), out[3..5] = emb[idx]; float4 lanes
__global__ __launch_bounds__(256) void init_out_k(
    const float* __restrict__ emb, const int* __restrict__ n0,
    const int* __restrict__ n1, const int* __restrict__ n2,
    float* __restrict__ out, int B)
{
    int tid = blockIdx.x * blockDim.x + threadIdx.x;
    int total = 3 * B * 16;                 // float4 granularity
    if (tid >= total) return;
    int arr = tid / (B * 16);
    int rem = tid - arr * (B * 16);
    int b = rem >> 4;
    int d4 = rem & 15;
    const int* __restrict__ idx = (arr == 0) ? n0 : ((arr == 1) ? n1 : n2);
    float4 v = *(const float4*)(emb + (long)idx[b] * 64 + d4 * 4);
    float4 q = make_float4(0.25f * v.x, 0.25f * v.y, 0.25f * v.z, 0.25f * v.w);
    *(float4*)(out + (long)arr * B * 64 + (long)rem * 4) = q;
    *(float4*)(out + (long)(arr + 3) * B * 64 + (long)rem * 4) = v;
}

// pooled += 0.25 * agg_bf16[idx]
__global__ __launch_bounds__(256) void gather_add_k(
    const ushort* __restrict__ agg, const int* __restrict__ n0,
    const int* __restrict__ n1, const int* __restrict__ n2,
    float* __restrict__ out, int B)
{
    int tid = blockIdx.x * blockDim.x + threadIdx.x;
    int total = 3 * B * 16;
    if (tid >= total) return;
    int arr = tid / (B * 16);
    int rem = tid - arr * (B * 16);
    int b = rem >> 4;
    int d4 = rem & 15;
    const int* __restrict__ idx = (arr == 0) ? n0 : ((arr == 1) ? n1 : n2);
    ushort4 v = *(const ushort4*)(agg + (long)idx[b] * 64 + d4 * 4);
    float* o = out + (long)arr * B * 64 + (long)rem * 4;
    float4 cur = *(float4*)o;
    cur.x += 0.25f * bf2f(v.x); cur.y += 0.25f * bf2f(v.y);
    cur.z += 0.25f * bf2f(v.z); cur.w += 0.25f * bf2f(v.w);
    *(float4*)o = cur;
}

extern "C" void kernel_launch(void* const* d_in, const int* in_sizes, int n_in,
                              void* d_out, int out_size, void* d_ws, size_t ws_size,
                              hipStream_t stream)
{
    const float* emb  = (const float*)d_in[0];
    const int*   rows = (const int*)d_in[1];
    const int*   cols = (const int*)d_in[2];
    const float* vals = (const float*)d_in[3];
    const int*   node = (const int*)d_in[4];
    const int*   pos  = (const int*)d_in[5];
    const int*   neg  = (const int*)d_in[6];
    float* out = (float*)d_out;

    const int E = in_sizes[1];
    const int B = in_sizes[4];
    const int N = in_sizes[0] / 64;
    const size_t nd = (size_t)N * 64;
    const int chunkE = (E + NCHUNK - 1) / NCHUNK;
    const int nbucket = (N + BMASK) >> BSHIFT;     // 6250 for N=100000

    // workspace layout
    ushort* aggA        = (ushort*)d_ws;            // N*64 bf16
    ushort* aggB        = aggA + nd;                // N*64 bf16 (also emb cast)
    int2*  edges        = (int2*)(aggB + nd);       // E (bucket-grouped)
    int2*  edges2       = edges + E;                // E (row-sorted)
    int*   cnt          = (int*)(edges2 + E);       // NCHUNK * NBUCKET
    int*   totals       = cnt + (long)NCHUNK * NBUCKET;  // NBUCKET
    int*   bucket_start = totals + NBUCKET;         // NBUCKET+1
    int*   row_start    = bucket_start + NBUCKET + 1;    // N+1
    // offs reuses edges2's storage: written by localscan, read by scatter3,
    // dead before sort_bkt writes edges2 (stream-ordered).
    int*   offs         = (int*)edges2;             // NCHUNK * NBUCKET

    const int gtotal   = 3 * B * 16;
    const int gblocks  = (gtotal + 255) / 256;
    const int cblocks  = ((int)(nd / 4) + 255) / 256;
    const int bblocks  = (nbucket + 255) / 256;     // 25
    const int dblocks  = (nbucket + 3) / 4;         // sortD: 4 buckets/block
    const int rblocks  = (N + 3) / 4;               // spmm: 4 rows/block

    init_out_k<<<gblocks, 256, 0, stream>>>(emb, node, pos, neg, out, B);
    f2bf_k<<<cblocks, 256, 0, stream>>>(emb, aggB, (int)(nd / 4));

    // ---- bucketed partition + per-bucket counting sort; no global atomics ----
    count_k<<<NCHUNK, 1024, 0, stream>>>(rows, cnt, E, chunkE);
    localscan_k<<<bblocks, 256, 0, stream>>>(cnt, offs, totals);
    scan_fused_k<<<1, 1024, 0, stream>>>(totals, bucket_start, nbucket);
    scatter3_k<<<NCHUNK, 1024, 0, stream>>>(rows, cols, vals, offs, bucket_start, edges, E, chunkE);
    sort_bkt_k<<<dblocks, 256, 0, stream>>>(bucket_start, edges, edges2, row_start, nbucket);

    // ---- 3 propagation hops, row-wave register-accumulating spmm ----
    spmm_csr_k<<<rblocks, 256, 0, stream>>>(row_start, edges2, aggB, aggA, N);
    gather_add_k<<<gblocks, 256, 0, stream>>>(aggA, node, pos, neg, out, B);

    spmm_csr_k<<<rblocks, 256, 0, stream>>>(row_start, edges2, aggA, aggB, N);
    gather_add_k<<<gblocks, 256, 0, stream>>>(aggB, node, pos, neg, out, B);

    spmm_csr_k<<<rblocks, 256, 0, stream>>>(row_start, edges2, aggB, aggA, N);
    gather_add_k<<<gblocks, 256, 0, stream>>>(aggA, node, pos, neg, out, B);
}

// Round 12
// 203.656 us; speedup vs baseline: 9.3927x; 1.0771x over previous
//
#include <hip/hip_runtime.h>

// LightGCN 3-hop propagation, D=64, bf16 features / fp32 accumulate.
// R11: (1) spmm with 16 static register chains (rows avg 16 edges -> most
// rows finish in ONE batch = one memory round-trip; 2x loads in flight).
// (2) 32-row buckets (NBUCKET=3125): halves cnt/localscan traffic and
// scatter3 write amplification; sort_bkt uses 32 LDS cursors per wave.

#define NBUCKET 3125     // N=100000 rows, 32 per bucket
#define BSHIFT  5
#define BMASK   31
#define NCHUNK  256      // edge chunks; E=1.6M -> 6250 edges/chunk

static __device__ __forceinline__ ushort f2bf(float f) {
    unsigned u = __float_as_uint(f);
    unsigned r = (u + 0x7fffu + ((u >> 16) & 1u)) >> 16;   // RNE
    return (ushort)r;
}
static __device__ __forceinline__ float bf2f(ushort b) {
    return __uint_as_float(((unsigned)b) << 16);
}

__global__ __launch_bounds__(256) void f2bf_k(
    const float* __restrict__ in, ushort* __restrict__ out, int n4)
{
    int i = blockIdx.x * blockDim.x + threadIdx.x;
    if (i >= n4) return;
    float4 v = *(const float4*)(in + (long)i * 4);
    ushort4 o;
    o.x = f2bf(v.x); o.y = f2bf(v.y); o.z = f2bf(v.z); o.w = f2bf(v.w);
    *(ushort4*)(out + (long)i * 4) = o;
}

// pass A: per-chunk bucket histogram in LDS (no global atomics); 16 waves
__global__ __launch_bounds__(1024) void count_k(
    const int* __restrict__ rows, int* __restrict__ cnt, int E, int chunkE)
{
    __shared__ unsigned h[NBUCKET];
    int c = blockIdx.x;
    for (int b = threadIdx.x; b < NBUCKET; b += 1024) h[b] = 0u;
    __syncthreads();
    int s = c * chunkE;
    int e = min(s + chunkE, E);
    for (int j = s + (int)threadIdx.x; j < e; j += 1024)
        atomicAdd(&h[rows[j] >> BSHIFT], 1u);
    __syncthreads();
    int* o = cnt + (long)c * NBUCKET;
    for (int b = threadIdx.x; b < NBUCKET; b += 1024) o[b] = (int)h[b];
}

// pass B: per-bucket local exclusive prefix over chunks + bucket totals.
__global__ __launch_bounds__(256) void localscan_k(
    const int* __restrict__ cnt, int* __restrict__ offs,
    int* __restrict__ totals)
{
    int b = blockIdx.x * 256 + threadIdx.x;
    if (b >= NBUCKET) return;
    int run = 0;
    #pragma unroll 8
    for (int c = 0; c < NCHUNK; ++c) {
        long i = (long)c * NBUCKET + b;
        int v = cnt[i];
        offs[i] = run;
        run += v;
    }
    totals[b] = run;
}

// fused exclusive scan over nbucket elements; single block of 1024
__global__ __launch_bounds__(1024) void scan_fused_k(
    const int* __restrict__ totals, int* __restrict__ bucket_start, int nbucket)
{
    __shared__ int sm[1024];
    __shared__ int carry_s;
    if (threadIdx.x == 0) carry_s = 0;
    __syncthreads();
    int ntile = (nbucket + 1023) / 1024;
    for (int t = 0; t < ntile; ++t) {
        int i = t * 1024 + threadIdx.x;
        int v = (i < nbucket) ? totals[i] : 0;
        sm[threadIdx.x] = v;
        __syncthreads();
        for (int off = 1; off < 1024; off <<= 1) {
            int add = (threadIdx.x >= off) ? sm[threadIdx.x - off] : 0;
            __syncthreads();
            sm[threadIdx.x] += add;
            __syncthreads();
        }
        int c0 = carry_s;
        if (i < nbucket) bucket_start[i] = c0 + sm[threadIdx.x] - v;
        __syncthreads();
        if (threadIdx.x == 1023) carry_s = c0 + sm[1023];
        __syncthreads();
    }
    if (threadIdx.x == 0) bucket_start[nbucket] = carry_s;   // == E
}

// pass C: partition edges into bucket segments; LDS cursors only; 16 waves.
// edge payload: .x = (row&31)<<17 | col  (col < 2^17), .y = val bits
__global__ __launch_bounds__(1024) void scatter3_k(
    const int* __restrict__ rows, const int* __restrict__ cols,
    const float* __restrict__ vals, const int* __restrict__ offs,
    const int* __restrict__ bucket_start,
    int2* __restrict__ edges, int E, int chunkE)
{
    __shared__ int cur[NBUCKET];
    int c = blockIdx.x;
    const int* o = offs + (long)c * NBUCKET;
    for (int b = threadIdx.x; b < NBUCKET; b += 1024)
        cur[b] = o[b] + bucket_start[b];
    __syncthreads();
    int s = c * chunkE;
    int e = min(s + chunkE, E);
    for (int j = s + (int)threadIdx.x; j < e; j += 1024) {
        int r = rows[j];
        int pos = atomicAdd(&cur[r >> BSHIFT], 1);
        edges[pos] = make_int2(((r & BMASK) << 17) | cols[j],
                               __float_as_int(vals[j]));
    }
}

// pass D: per-bucket LDS counting sort over the 32 row-locals.
// One wave per bucket; intra-wave program order -> no barriers needed.
__global__ __launch_bounds__(256) void sort_bkt_k(
    const int* __restrict__ bucket_start, const int2* __restrict__ edges_in,
    int2* __restrict__ edges_out, int* __restrict__ row_start, int nbucket)
{
    __shared__ int cur[4][32];
    int w = (int)(threadIdx.x >> 6);
    int lane = (int)(threadIdx.x & 63);
    int bk = blockIdx.x * 4 + w;
    if (bk >= nbucket) return;
    int s = bucket_start[bk];
    int e = bucket_start[bk + 1];
    if (lane < 32) cur[w][lane] = 0;
    for (int j = s + lane; j < e; j += 64)
        atomicAdd(&cur[w][(unsigned)edges_in[j].x >> 17], 1);
    if (lane == 0) {
        int run = s;
        #pragma unroll
        for (int r = 0; r < 32; ++r) {
            int c = cur[w][r];
            cur[w][r] = run;
            row_start[bk * 32 + r] = run;
            run += c;
        }
    }
    for (int j = s + lane; j < e; j += 64) {
        int2 ed = edges_in[j];
        int pos = atomicAdd(&cur[w][(unsigned)ed.x >> 17], 1);
        edges_out[pos] = ed;
    }
    if (bk == nbucket - 1 && lane == 0) row_start[nbucket * 32] = e;  // == E
}

#define GMA(k) float p##k = __int_as_float(ee##k.y) * \
    bf2f(x[(long)(ee##k.x & 0x1FFFF) * 64 + d])

// spmm: one wave per row; lane = feature dim; scalar edge stream;
// 16 static register chains (one round-trip for rows <=16 edges).
__global__ __launch_bounds__(256) void spmm_csr_k(
    const int* __restrict__ row_start, const int2* __restrict__ edges,
    const ushort* __restrict__ x, ushort* __restrict__ y, int N)
{
    int wid = __builtin_amdgcn_readfirstlane((int)(threadIdx.x >> 6));
    int r = blockIdx.x * 4 + wid;
    if (r >= N) return;
    int d = (int)(threadIdx.x & 63);
    int s = row_start[r];      // wave-uniform -> s_load
    int e = row_start[r + 1];
    float a0 = 0.f, a1 = 0.f, a2 = 0.f, a3 = 0.f;
    float a4 = 0.f, a5 = 0.f, a6 = 0.f, a7 = 0.f;
    float a8 = 0.f, a9 = 0.f, a10 = 0.f, a11 = 0.f;
    float a12 = 0.f, a13 = 0.f, a14 = 0.f, a15 = 0.f;
    int j = s;
    for (; j + 16 <= e; j += 16) {
        int2 ee0  = edges[j];      int2 ee1  = edges[j + 1];
        int2 ee2  = edges[j + 2];  int2 ee3  = edges[j + 3];
        int2 ee4  = edges[j + 4];  int2 ee5  = edges[j + 5];
        int2 ee6  = edges[j + 6];  int2 ee7  = edges[j + 7];
        int2 ee8  = edges[j + 8];  int2 ee9  = edges[j + 9];
        int2 ee10 = edges[j + 10]; int2 ee11 = edges[j + 11];
        int2 ee12 = edges[j + 12]; int2 ee13 = edges[j + 13];
        int2 ee14 = edges[j + 14]; int2 ee15 = edges[j + 15];
        GMA(0); GMA(1); GMA(2); GMA(3); GMA(4); GMA(5); GMA(6); GMA(7);
        GMA(8); GMA(9); GMA(10); GMA(11); GMA(12); GMA(13); GMA(14); GMA(15);
        a0 += p0;  a1 += p1;  a2 += p2;  a3 += p3;
        a4 += p4;  a5 += p5;  a6 += p6;  a7 += p7;
        a8 += p8;  a9 += p9;  a10 += p10; a11 += p11;
        a12 += p12; a13 += p13; a14 += p14; a15 += p15;
    }
    for (; j + 8 <= e; j += 8) {
        int2 ee0 = edges[j];     int2 ee1 = edges[j + 1];
        int2 ee2 = edges[j + 2]; int2 ee3 = edges[j + 3];
        int2 ee4 = edges[j + 4]; int2 ee5 = edges[j + 5];
        int2 ee6 = edges[j + 6]; int2 ee7 = edges[j + 7];
        GMA(0); GMA(1); GMA(2); GMA(3); GMA(4); GMA(5); GMA(6); GMA(7);
        a0 += p0; a1 += p1; a2 += p2; a3 += p3;
        a4 += p4; a5 += p5; a6 += p6; a7 += p7;
    }
    for (; j + 4 <= e; j += 4) {
        int2 ee0 = edges[j];     int2 ee1 = edges[j + 1];
        int2 ee2 = edges[j + 2]; int2 ee3 = edges[j + 3];
        GMA(0); GMA(1); GMA(2); GMA(3);
        a0 += p0; a1 += p1; a2 += p2; a3 += p3;
    }
    for (; j < e; ++j) {
        int2 ee0 = edges[j];
        GMA(0);
        a0 += p0;
    }
    float sum = (((a0 + a1) + (a2 + a3)) + ((a4 + a5) + (a6 + a7)))
              + (((a8 + a9) + (a10 + a11)) + ((a12 + a13) + (a14 + a15)));
    y[(long)r * 64 + d] = f2bf(sum);
}

// out[0..2] = 0.25*emb[idx] (hop-0 term), out[3..5] = emb[idx]; float4 lanes
__global__ __launch_bounds__(256) void init_out_k(
    const float* __restrict__ emb, const int* __restrict__ n0,
    const int* __restrict__ n1, const int* __restrict__ n2,
    float* __restrict__ out, int B)
{
    int tid = blockIdx.x * blockDim.x + threadIdx.x;
    int total = 3 * B * 16;                 // float4 granularity
    if (tid >= total) return;
    int arr = tid / (B * 16);
    int rem = tid - arr * (B * 16);
    int b = rem >> 4;
    int d4 = rem & 15;
    const int* __restrict__ idx = (arr == 0) ? n0 : ((arr == 1) ? n1 : n2);
    float4 v = *(const float4*)(emb + (long)idx[b] * 64 + d4 * 4);
    float4 q = make_float4(0.25f * v.x, 0.25f * v.y, 0.25f * v.z, 0.25f * v.w);
    *(float4*)(out + (long)arr * B * 64 + (long)rem * 4) = q;
    *(float4*)(out + (long)(arr + 3) * B * 64 + (long)rem * 4) = v;
}

// pooled += 0.25 * agg_bf16[idx]
__global__ __launch_bounds__(256) void gather_add_k(
    const ushort* __restrict__ agg, const int* __restrict__ n0,
    const int* __restrict__ n1, const int* __restrict__ n2,
    float* __restrict__ out, int B)
{
    int tid = blockIdx.x * blockDim.x + threadIdx.x;
    int total = 3 * B * 16;
    if (tid >= total) return;
    int arr = tid / (B * 16);
    int rem = tid - arr * (B * 16);
    int b = rem >> 4;
    int d4 = rem & 15;
    const int* __restrict__ idx = (arr == 0) ? n0 : ((arr == 1) ? n1 : n2);
    ushort4 v = *(const ushort4*)(agg + (long)idx[b] * 64 + d4 * 4);
    float* o = out + (long)arr * B * 64 + (long)rem * 4;
    float4 cur = *(float4*)o;
    cur.x += 0.25f * bf2f(v.x); cur.y += 0.25f * bf2f(v.y);
    cur.z += 0.25f * bf2f(v.z); cur.w += 0.25f * bf2f(v.w);
    *(float4*)o = cur;
}

extern "C" void kernel_launch(void* const* d_in, const int* in_sizes, int n_in,
                              void* d_out, int out_size, void* d_ws, size_t ws_size,
                              hipStream_t stream)
{
    const float* emb  = (const float*)d_in[0];
    const int*   rows = (const int*)d_in[1];
    const int*   cols = (const int*)d_in[2];
    const float* vals = (const float*)d_in[3];
    const int*   node = (const int*)d_in[4];
    const int*   pos  = (const int*)d_in[5];
    const int*   neg  = (const int*)d_in[6];
    float* out = (float*)d_out;

    const int E = in_sizes[1];
    const int B = in_sizes[4];
    const int N = in_sizes[0] / 64;
    const size_t nd = (size_t)N * 64;
    const int chunkE = (E + NCHUNK - 1) / NCHUNK;
    const int nbucket = (N + BMASK) >> BSHIFT;     // 3125 for N=100000

    // workspace layout
    ushort* aggA        = (ushort*)d_ws;            // N*64 bf16
    ushort* aggB        = aggA + nd;                // N*64 bf16 (also emb cast)
    int2*  edges        = (int2*)(aggB + nd);       // E (bucket-grouped)
    int2*  edges2       = edges + E;                // E (row-sorted)
    int*   cnt          = (int*)(edges2 + E);       // NCHUNK * NBUCKET
    int*   totals       = cnt + (long)NCHUNK * NBUCKET;  // NBUCKET
    int*   bucket_start = totals + NBUCKET;         // NBUCKET+1
    int*   row_start    = bucket_start + NBUCKET + 1;    // nbucket*32+1
    // offs reuses edges2's storage (dead before sort_bkt writes edges2)
    int*   offs         = (int*)edges2;             // NCHUNK * NBUCKET

    const int gtotal   = 3 * B * 16;
    const int gblocks  = (gtotal + 255) / 256;
    const int cblocks  = ((int)(nd / 4) + 255) / 256;
    const int bblocks  = (nbucket + 255) / 256;     // 13
    const int dblocks  = (nbucket + 3) / 4;         // sortD: 4 buckets/block
    const int rblocks  = (N + 3) / 4;               // spmm: 4 rows/block

    init_out_k<<<gblocks, 256, 0, stream>>>(emb, node, pos, neg, out, B);
    f2bf_k<<<cblocks, 256, 0, stream>>>(emb, aggB, (int)(nd / 4));

    // ---- bucketed partition + per-bucket counting sort; no global atomics ----
    count_k<<<NCHUNK, 1024, 0, stream>>>(rows, cnt, E, chunkE);
    localscan_k<<<bblocks, 256, 0, stream>>>(cnt, offs, totals);
    scan_fused_k<<<1, 1024, 0, stream>>>(totals, bucket_start, nbucket);
    scatter3_k<<<NCHUNK, 1024, 0, stream>>>(rows, cols, vals, offs, bucket_start, edges, E, chunkE);
    sort_bkt_k<<<dblocks, 256, 0, stream>>>(bucket_start, edges, edges2, row_start, nbucket);

    // ---- 3 propagation hops, row-wave register-accumulating spmm ----
    spmm_csr_k<<<rblocks, 256, 0, stream>>>(row_start, edges2, aggB, aggA, N);
    gather_add_k<<<gblocks, 256, 0, stream>>>(aggA, node, pos, neg, out, B);

    spmm_csr_k<<<rblocks, 256, 0, stream>>>(row_start, edges2, aggA, aggB, N);
    gather_add_k<<<gblocks, 256, 0, stream>>>(aggB, node, pos, neg, out, B);

    spmm_csr_k<<<rblocks, 256, 0, stream>>>(row_start, edges2, aggB, aggA, N);
    gather_add_k<<<gblocks, 256, 0, stream>>>(aggA, node, pos, neg, out, B);
}